// Round 11
// baseline (595.941 us; speedup 1.0000x reference)
//
#include <hip/hip_runtime.h>
#include <hip/hip_bf16.h>

#define NN   100000
#define HIDD 128
#define NB   782          // ceil(NN/128) buckets of 128 nodes

typedef __attribute__((ext_vector_type(8))) short bf16x8;
typedef __attribute__((ext_vector_type(4))) float f32x4;

// RNE fp32 -> bf16 bits
__device__ __forceinline__ short bf16_rne(float v) {
    unsigned u = __float_as_uint(v);
    unsigned r = (u + 0x7fffu + ((u >> 16) & 1u)) >> 16;
    return (short)r;
}
__device__ __forceinline__ float bf16_to_f32(short b) {
    return __uint_as_float(((unsigned)(unsigned short)b) << 16);
}
__device__ __forceinline__ float bf16u_to_f32(ushort b) {
    return __uint_as_float(((unsigned)b) << 16);
}
__device__ __forceinline__ unsigned pack2(float a, float b) {
    return ((unsigned)(unsigned short)bf16_rne(a)) |
           (((unsigned)(unsigned short)bf16_rne(b)) << 16);
}

// ---------------------------------------------------------------------------
// Bucketed CSR build. bucket = dst >> 7 (128 nodes per bucket).
// ---------------------------------------------------------------------------
__global__ __launch_bounds__(256)
void bucket_hist(const int* __restrict__ edges, int n_edges,
                 int* __restrict__ bcnt) {
    __shared__ int lh[NB];
    for (int i = threadIdx.x; i < NB; i += 256) lh[i] = 0;
    __syncthreads();
    int stride = gridDim.x * blockDim.x;
    for (int e = blockIdx.x * blockDim.x + threadIdx.x; e < n_edges; e += stride) {
        int d = edges[n_edges + e];
        if ((unsigned)d < NN) atomicAdd(&lh[d >> 7], 1);
    }
    __syncthreads();
    for (int i = threadIdx.x; i < NB; i += 256)
        if (lh[i]) atomicAdd(&bcnt[i], lh[i]);
}

__global__ void scan_bptr(const int* __restrict__ bcnt, int* __restrict__ bptr) {
    __shared__ int lds[1024];
    int t = threadIdx.x;
    lds[t] = (t < NB) ? bcnt[t] : 0;
    __syncthreads();
    for (int off = 1; off < 1024; off <<= 1) {
        int u = (t >= off) ? lds[t - off] : 0;
        __syncthreads();
        lds[t] += u;
        __syncthreads();
    }
    if (t < NB) bptr[t + 1] = lds[t];
    if (t == 0) bptr[0] = 0;
}

// Scatter edges into bucket regions as packed (dst_local<<17 | src).
#define SCAT_CHUNK 2048
__global__ __launch_bounds__(256)
void bucket_scatter(const int* __restrict__ edges, int n_edges,
                    const int* __restrict__ bptr, int* __restrict__ bcur,
                    int* __restrict__ bedges) {
    __shared__ int lh[NB];
    __shared__ int lbase[NB];
    int t = threadIdx.x;
    int base = blockIdx.x * SCAT_CHUNK;
    for (int i = t; i < NB; i += 256) lh[i] = 0;
    __syncthreads();
#pragma unroll
    for (int i = 0; i < SCAT_CHUNK / 256; ++i) {
        int e = base + i * 256 + t;
        if (e < n_edges) {
            int d = edges[n_edges + e];
            if ((unsigned)d < NN) atomicAdd(&lh[d >> 7], 1);
        }
    }
    __syncthreads();
    for (int i = t; i < NB; i += 256) {
        int c = lh[i];
        lbase[i] = (c > 0) ? atomicAdd(&bcur[i], c) : 0;
        lh[i] = 0;   // reuse as cursor
    }
    __syncthreads();
#pragma unroll
    for (int i = 0; i < SCAT_CHUNK / 256; ++i) {
        int e = base + i * 256 + t;
        if (e < n_edges) {
            int s = edges[e];
            int d = edges[n_edges + e];
            if ((unsigned)d < NN && (unsigned)s < NN) {
                int b = d >> 7;
                int off = atomicAdd(&lh[b], 1);
                bedges[bptr[b] + lbase[b] + off] = ((d & 127) << 17) | s;
            }
        }
    }
}

// One block per bucket: local count -> scan -> place. Emits row_ptr + col_src.
__global__ __launch_bounds__(256)
void bucket_csr(const int* __restrict__ bedges, const int* __restrict__ bptr,
                int* __restrict__ row_ptr, int* __restrict__ col_src) {
    __shared__ int lcnt[128];
    __shared__ int lexcl[128];
    int b = blockIdx.x;
    int t = threadIdx.x;
    int beg = bptr[b], end = bptr[b + 1];
    if (t < 128) lcnt[t] = 0;
    __syncthreads();
    for (int e = beg + t; e < end; e += 256)
        atomicAdd(&lcnt[bedges[e] >> 17], 1);
    __syncthreads();
    if (t < 128) lexcl[t] = lcnt[t];
    __syncthreads();
    for (int off = 1; off < 128; off <<= 1) {
        int u = (t < 128 && t >= off) ? lexcl[t - off] : 0;
        __syncthreads();
        if (t < 128) lexcl[t] += u;
        __syncthreads();
    }
    int node0 = b << 7;
    if (t < 128) {
        int excl = lexcl[t] - lcnt[t];   // exclusive scan
        int node = node0 + t;
        if (node < NN) row_ptr[node] = beg + excl;
        lexcl[t] = excl;
        lcnt[t] = 0;                     // reuse as cursor
    }
    if (b == NB - 1 && t == 0) row_ptr[NN] = end;
    __syncthreads();
    for (int e = beg + t; e < end; e += 256) {
        int p = bedges[e];
        int dl = p >> 17, src = p & 0x1FFFF;
        int pos = atomicAdd(&lcnt[dl], 1);
        col_src[beg + lexcl[dl] + pos] = src;
    }
}

// ---------------------------------------------------------------------------
// fp32 -> bf16 conversion (x)
// ---------------------------------------------------------------------------
__global__ void to_bf16(const float* __restrict__ in, ushort* __restrict__ out, int n) {
    int i = (blockIdx.x * blockDim.x + threadIdx.x) * 4;
    if (i + 3 >= n) {
        for (int k = i; k < n; ++k) out[k] = (ushort)bf16_rne(in[k]);
        return;
    }
    float4 v = *(const float4*)&in[i];
    unsigned lo = pack2(v.x, v.y), hi = pack2(v.z, v.w);
    *(uint2*)&out[i] = make_uint2(lo, hi);
}

// ---------------------------------------------------------------------------
// XCD-sliced mean aggregation (HIDD=128).
// 8 feature-slices of 16 features (32B of each 256B row); slice = blockIdx%8.
// Block dispatch round-robins across the 8 XCDs, so each XCD touches only its
// slice's column of h16: 100K*16*2B = 3.2MB < 4MB per-XCD L2 -> gather becomes
// L2-resident (r10: cross-XCD duplication made FETCH=178MB for 25.6MB data).
// Block = 4 waves = 16 nodes (4 nodes/wave, 16 lanes each). Within 16 lanes:
// g=q>>1 indexes 8 neighbors/batch, p=q&1 the 16B half-slice. Masked loop
// handles degree variance; reduce = shfl_xor 2/4/8; lanes q<2 write 32B.
// 100000 = 6250*16 exact -> no node tail. Grid = 6250*8.
// ---------------------------------------------------------------------------
__global__ __launch_bounds__(256)
void aggregate128_xcd(const ushort* __restrict__ h16,
                      const int* __restrict__ row_ptr,
                      const int* __restrict__ col_src,
                      ushort* __restrict__ aggr16) {
    const int slice = blockIdx.x & 7;
    const int nb    = blockIdx.x >> 3;
    const int t = threadIdx.x;
    const int wave = t >> 6, lane = t & 63;
    const int sub = lane >> 4;          // node within wave 0..3
    const int q   = lane & 15;
    const int g   = q >> 1;             // neighbor group 0..7
    const int p   = q & 1;              // 16B half of the 32B slice
    const int node = nb * 16 + wave * 4 + sub;

    const int beg = row_ptr[node], end = row_ptr[node + 1];
    const size_t foff = slice * 16 + p * 8;
    float s[8] = {0.f, 0.f, 0.f, 0.f, 0.f, 0.f, 0.f, 0.f};
    int j = beg + g;
    while (__any(j < end)) {
        if (j < end) {
            int idx = col_src[j];
            bf16x8 v = *(const bf16x8*)&h16[(size_t)idx * HIDD + foff];
#pragma unroll
            for (int e = 0; e < 8; ++e) s[e] += bf16u_to_f32((ushort)v[e]);
        }
        j += 8;
    }
    // reduce across the 8 neighbor groups (lane bits 1..3)
#pragma unroll
    for (int e = 0; e < 8; ++e) {
        s[e] += __shfl_xor(s[e], 2);
        s[e] += __shfl_xor(s[e], 4);
        s[e] += __shfl_xor(s[e], 8);
    }
    if (q < 2) {
        float inv = (end > beg) ? 1.0f / (float)(end - beg) : 0.0f;
        unsigned r0 = pack2(s[0] * inv, s[1] * inv);
        unsigned r1 = pack2(s[2] * inv, s[3] * inv);
        unsigned r2 = pack2(s[4] * inv, s[5] * inv);
        unsigned r3 = pack2(s[6] * inv, s[7] * inv);
        *(uint4*)&aggr16[(size_t)node * HIDD + foff] = make_uint4(r0, r1, r2, r3);
    }
}

// One wave per node; 4 lanes x 16B cover one 64B row; 16 groups =>
// 16 neighbors per load instruction. deg~16 => ~1 batch + masked tail.
__global__ void aggregate32_bf16(const ushort* __restrict__ x16,
                                 const int* __restrict__ row_ptr,
                                 const int* __restrict__ col_src,
                                 ushort* __restrict__ aggr16, int n_nodes) {
    int node = (int)((blockIdx.x * (size_t)blockDim.x + threadIdx.x) >> 6);
    int lane = threadIdx.x & 63;
    if (node >= n_nodes) return;
    const int g   = lane >> 2;        // neighbor group 0..15
    const int seg = lane & 3;         // 16B segment within 64B row
    int beg = row_ptr[node], end = row_ptr[node + 1];
    float s[8] = {0.f, 0.f, 0.f, 0.f, 0.f, 0.f, 0.f, 0.f};
    int j = beg;
    for (; j + 16 <= end; j += 16) {
        int i0 = col_src[j + g];
        bf16x8 v0 = *(const bf16x8*)&x16[(size_t)i0 * 32 + seg * 8];
#pragma unroll
        for (int e = 0; e < 8; ++e) s[e] += bf16u_to_f32((ushort)v0[e]);
    }
    int rem = end - j;
    if (g < rem) {                                 // masked tail (up to 15)
        int i0 = col_src[j + g];
        bf16x8 v0 = *(const bf16x8*)&x16[(size_t)i0 * 32 + seg * 8];
#pragma unroll
        for (int e = 0; e < 8; ++e) s[e] += bf16u_to_f32((ushort)v0[e]);
    }
    // reduce across the 16 groups
#pragma unroll
    for (int e = 0; e < 8; ++e) {
        s[e] += __shfl_xor(s[e], 4);
        s[e] += __shfl_xor(s[e], 8);
        s[e] += __shfl_xor(s[e], 16);
        s[e] += __shfl_xor(s[e], 32);
    }
    float inv = (end > beg) ? 1.0f / (float)(end - beg) : 0.0f;
    if (lane < 4) {
        unsigned r0 = pack2(s[0] * inv, s[1] * inv);
        unsigned r1 = pack2(s[2] * inv, s[3] * inv);
        unsigned r2 = pack2(s[4] * inv, s[5] * inv);
        unsigned r3 = pack2(s[6] * inv, s[7] * inv);
        *(uint4*)&aggr16[(size_t)node * 32 + seg * 8] = make_uint4(r0, r1, r2, r3);
    }
}

// ---------------------------------------------------------------------------
// Weight pre-split: fp32 -> (hi, lo) bf16 planes, all 6 conv matrices.
// ---------------------------------------------------------------------------
__global__ void split_weights(const float* __restrict__ W1l, const float* __restrict__ W1r,
                              const float* __restrict__ W2l, const float* __restrict__ W2r,
                              const float* __restrict__ W3l, const float* __restrict__ W3r,
                              short* __restrict__ whi, short* __restrict__ wlo) {
    int i = blockIdx.x * blockDim.x + threadIdx.x;
    if (i >= 73728) return;
    const float* src; int off;
    if (i < 4096)       { src = W1l; off = 0; }
    else if (i < 8192)  { src = W1r; off = 4096; }
    else if (i < 24576) { src = W2l; off = 8192; }
    else if (i < 40960) { src = W2r; off = 24576; }
    else if (i < 57344) { src = W3l; off = 40960; }
    else                { src = W3r; off = 57344; }
    float v = src[i - off];
    short h = bf16_rne(v);
    float l = v - bf16_to_f32(h);
    whi[i] = h;
    wlo[i] = bf16_rne(l);
}

// ---------------------------------------------------------------------------
// LDS-staged MFMA dual GEMM (r9 structure, unchanged — left top-5).
// ---------------------------------------------------------------------------
template <int KA, bool RELU, bool MEAN>
__global__ __launch_bounds__(256, 2)
void gemm_lds(const ushort* __restrict__ inA, const ushort* __restrict__ inB,
              const short* __restrict__ WAhi, const short* __restrict__ WAlo,
              const short* __restrict__ WBhi, const short* __restrict__ WBlo,
              const float* __restrict__ bias,
              ushort* __restrict__ out, float* __restrict__ gsum) {
    constexpr int NCH   = KA / 32;     // k-chunks
    constexpr int NFRAG = 4 * NCH;     // W frags per 16-col strip (2op x NCH x 2pl)
    constexpr int NTILE = NN / 32;     // 3125 row tiles, exact
    __shared__ ushort sW[8192 * NCH];  // 16KB * NCH (64KB at KA=128)

    const int t = threadIdx.x;
    const int wave = t >> 6, lane = t & 63;
    const int lcol = lane & 15;        // B col within strip / A row within tile
    const int koff = lane >> 4;        // which 16B k-chunk of the fragment
    const int half = blockIdx.x & 1;
    const int o0 = half * 64 + wave * 16;

    // ---- cooperative W staging into LDS (swizzled) ----
    for (int i = t; i < 1024 * NCH; i += 256) {
        int tile = i >> 6;             // [0, 16*NCH): (strip, frag)
        int w2 = i & 63;
        int c  = w2 >> 2;              // col 0..15
        int kf = w2 & 3;               // chunk 0..3
        int ws = tile / NFRAG;
        int f  = tile % NFRAG;
        int op = f / (NCH * 2);
        int rem = f % (NCH * 2);
        int ch = rem >> 1;
        int pl = rem & 1;
        const short* Wp = op ? (pl ? WBlo : WBhi) : (pl ? WAlo : WAhi);
        int cg = half * 64 + ws * 16 + c;
        bf16x8 v = *(const bf16x8*)&Wp[(size_t)cg * KA + ch * 32 + kf * 8];
        *(bf16x8*)&sW[ws * (2048 * NCH) + f * 512 + c * 32 + ((kf ^ (c & 3)) * 8)] = v;
    }
    __syncthreads();

    const int wbase = wave * (2048 * NCH) + lcol * 32 + ((koff ^ (lcol & 3)) * 8);
    const int lk8 = koff * 8;
    const float bv = MEAN ? 0.f : bias[o0 + lcol];
    const int rg = koff * 4;           // C row-group base
    float csum = 0.f;

    for (int rt = blockIdx.x >> 1; rt < NTILE; rt += (gridDim.x >> 1)) {
        const int r0 = rt * 32;
        // ---- A loads, all issued up front (independent) ----
        bf16x8 a0[2][NCH], a1[2][NCH];
#pragma unroll
        for (int op = 0; op < 2; ++op) {
            const ushort* __restrict__ in = op ? inB : inA;
            const ushort* p0 = in + (size_t)(r0 + lcol) * KA + lk8;
            const ushort* p1 = in + (size_t)(r0 + 16 + lcol) * KA + lk8;
#pragma unroll
            for (int ch = 0; ch < NCH; ++ch) {
                a0[op][ch] = *(const bf16x8*)(p0 + ch * 32);
                a1[op][ch] = *(const bf16x8*)(p1 + ch * 32);
            }
        }
        f32x4 acc0 = (f32x4){0.f, 0.f, 0.f, 0.f};
        f32x4 acc1 = (f32x4){0.f, 0.f, 0.f, 0.f};
#pragma unroll
        for (int op = 0; op < 2; ++op)
#pragma unroll
            for (int ch = 0; ch < NCH; ++ch)
#pragma unroll
                for (int pl = 0; pl < 2; ++pl) {
                    int f = (op * NCH + ch) * 2 + pl;
                    bf16x8 wf = *(const bf16x8*)&sW[wbase + f * 512];
                    acc0 = __builtin_amdgcn_mfma_f32_16x16x32_bf16(a0[op][ch], wf, acc0, 0, 0, 0);
                    acc1 = __builtin_amdgcn_mfma_f32_16x16x32_bf16(a1[op][ch], wf, acc1, 0, 0, 0);
                }
        if (!MEAN) {
            const int o = o0 + lcol;
#pragma unroll
            for (int r = 0; r < 4; ++r) {
                float v0 = acc0[r] + bv;
                if (RELU) v0 = fmaxf(v0, 0.f);
                out[(size_t)(r0 + rg + r) * HIDD + o] = (ushort)bf16_rne(v0);
                float v1 = acc1[r] + bv;
                if (RELU) v1 = fmaxf(v1, 0.f);
                out[(size_t)(r0 + 16 + rg + r) * HIDD + o] = (ushort)bf16_rne(v1);
            }
        } else {
            csum += ((acc0[0] + acc0[1]) + (acc0[2] + acc0[3]))
                  + ((acc1[0] + acc1[1]) + (acc1[2] + acc1[3]));
        }
    }

    if (MEAN) {
        float s = csum;
        s += __shfl_xor(s, 16);
        s += __shfl_xor(s, 32);
        if (lane < 16) atomicAdd(&gsum[o0 + lane], s);
    }
}

// ---------------------------------------------------------------------------
// Heads: g = gsum/N + b3; logits = relu(g@Pw1.T+Pb1)@Pw2.T+Pb2; value likewise.
// ---------------------------------------------------------------------------
__global__ void heads_kernel(const float* __restrict__ gsum,
                             const float* __restrict__ b3,
                             const float* __restrict__ Pw1, const float* __restrict__ Pb1,
                             const float* __restrict__ Pw2, const float* __restrict__ Pb2,
                             const float* __restrict__ Vw1, const float* __restrict__ Vb1,
                             const float* __restrict__ Vw2, const float* __restrict__ Vb2,
                             float* __restrict__ out, float inv_n) {
    __shared__ float g[128], a1[128], v1[128];
    int t = threadIdx.x;
    if (t < 128) g[t] = gsum[t] * inv_n + b3[t];
    __syncthreads();
    if (t < 128) {
        float s = Pb1[t];
        for (int f = 0; f < 128; ++f) s = fmaf(Pw1[t * 128 + f], g[f], s);
        a1[t] = fmaxf(s, 0.f);
    } else {
        int o = t - 128;
        float s = Vb1[o];
        for (int f = 0; f < 128; ++f) s = fmaf(Vw1[o * 128 + f], g[f], s);
        v1[o] = fmaxf(s, 0.f);
    }
    __syncthreads();
    if (t < 6) {
        float s = Pb2[t];
        for (int f = 0; f < 128; ++f) s = fmaf(Pw2[t * 128 + f], a1[f], s);
        out[t] = s;
    }
    if (t == 6) {
        float s = Vb2[0];
        for (int f = 0; f < 128; ++f) s = fmaf(Vw2[f], v1[f], s);
        out[6] = s;
    }
}

// ---------------------------------------------------------------------------
extern "C" void kernel_launch(void* const* d_in, const int* in_sizes, int n_in,
                              void* d_out, int out_size, void* d_ws, size_t ws_size,
                              hipStream_t stream) {
    const float* x    = (const float*)d_in[0];
    const int*   edges = (const int*)d_in[1];
    const float* W1l = (const float*)d_in[2];
    const float* b1  = (const float*)d_in[3];
    const float* W1r = (const float*)d_in[4];
    const float* W2l = (const float*)d_in[5];
    const float* b2  = (const float*)d_in[6];
    const float* W2r = (const float*)d_in[7];
    const float* W3l = (const float*)d_in[8];
    const float* b3  = (const float*)d_in[9];
    const float* W3r = (const float*)d_in[10];
    const float* Pw1 = (const float*)d_in[11];
    const float* Pb1 = (const float*)d_in[12];
    const float* Pw2 = (const float*)d_in[13];
    const float* Pb2 = (const float*)d_in[14];
    const float* Vw1 = (const float*)d_in[15];
    const float* Vb1 = (const float*)d_in[16];
    const float* Vw2 = (const float*)d_in[17];
    const float* Vb2 = (const float*)d_in[18];
    float* outp = (float*)d_out;

    const int E = in_sizes[1] / 2;

    // ---- workspace layout (int offsets, regions 256B-aligned) ----
    int*   ws_i = (int*)d_ws;
    float* ws_f = (float*)d_ws;
    size_t o_bcnt = 0;                 // NB ints   (zeroed)
    size_t o_bcur = 832;               // NB ints   (zeroed)
    size_t o_gsum = 1664;              // 128 f32   (zeroed)
    size_t o_bptr = 1792;              // NB+1
    size_t o_rowp = 2624;              // NN+1
    size_t o_bed  = 102656;            // E packed bucket edges
    size_t o_col  = o_bed + (size_t)E;           // E
    size_t o_whi  = ((o_col + (size_t)E + 63) / 64) * 64;  // 73728 shorts = 36864 ints
    size_t o_wlo  = o_whi + 36864;
    size_t o_x16  = o_wlo + 36864;               // NN*32 bf16 = NN*16 ints
    size_t o_aggr = o_x16 + (size_t)NN * 16;     // NN*128 bf16 = NN*64 ints
    size_t o_hA   = o_aggr + (size_t)NN * 64;
    size_t o_hB   = o_hA + (size_t)NN * 64;

    int*    bcnt    = ws_i + o_bcnt;
    int*    bcur    = ws_i + o_bcur;
    float*  gsum    = ws_f + o_gsum;
    int*    bptr    = ws_i + o_bptr;
    int*    row_ptr = ws_i + o_rowp;
    int*    bedges  = ws_i + o_bed;
    int*    col_src = ws_i + o_col;
    short*  whi     = (short*)(ws_i + o_whi);
    short*  wlo     = (short*)(ws_i + o_wlo);
    ushort* x16     = (ushort*)(ws_i + o_x16);
    ushort* aggr    = (ushort*)(ws_i + o_aggr);
    ushort* hA      = (ushort*)(ws_i + o_hA);
    ushort* hB      = (ushort*)(ws_i + o_hB);

    short* W1l_hi = whi + 0;     short* W1l_lo = wlo + 0;
    short* W1r_hi = whi + 4096;  short* W1r_lo = wlo + 4096;
    short* W2l_hi = whi + 8192;  short* W2l_lo = wlo + 8192;
    short* W2r_hi = whi + 24576; short* W2r_lo = wlo + 24576;
    short* W3l_hi = whi + 40960; short* W3l_lo = wlo + 40960;
    short* W3r_hi = whi + 57344; short* W3r_lo = wlo + 57344;

    // zero bcnt, bcur, gsum
    hipMemsetAsync(d_ws, 0, 1792 * sizeof(int), stream);

    const int TB = 256;
    dim3 blk(TB);

    // independent prep
    to_bf16<<<(NN * 32 / 4 + TB - 1) / TB, blk, 0, stream>>>(x, x16, NN * 32);
    split_weights<<<(73728 + TB - 1) / TB, blk, 0, stream>>>(
        W1l, W1r, W2l, W2r, W3l, W3r, whi, wlo);

    // bucketed CSR build
    bucket_hist<<<256, blk, 0, stream>>>(edges, E, bcnt);
    scan_bptr<<<1, 1024, 0, stream>>>(bcnt, bptr);
    bucket_scatter<<<(E + SCAT_CHUNK - 1) / SCAT_CHUNK, blk, 0, stream>>>(
        edges, E, bptr, bcur, bedges);
    bucket_csr<<<NB, blk, 0, stream>>>(bedges, bptr, row_ptr, col_src);

    dim3 grid_agg((size_t)NN * 64 / TB);   // 25000: one wave per node (K=32 agg)
    dim3 grid_axcd((NN / 16) * 8);         // 50000: 16 nodes/block x 8 slices
    dim3 grid_g(512);                      // 256 row-streaming blocks per col-half

    // Layer 1 (K=32, relu)
    aggregate32_bf16<<<grid_agg, blk, 0, stream>>>(x16, row_ptr, col_src, aggr, NN);
    gemm_lds<32, true, false><<<grid_g, blk, 0, stream>>>(
        aggr, x16, W1l_hi, W1l_lo, W1r_hi, W1r_lo, b1, hA, nullptr);

    // Layer 2 (K=128, relu)
    aggregate128_xcd<<<grid_axcd, blk, 0, stream>>>(hA, row_ptr, col_src, aggr);
    gemm_lds<128, true, false><<<grid_g, blk, 0, stream>>>(
        aggr, hA, W2l_hi, W2l_lo, W2r_hi, W2r_lo, b2, hB, nullptr);

    // Layer 3 (K=128, fused column-mean into gsum)
    aggregate128_xcd<<<grid_axcd, blk, 0, stream>>>(hB, row_ptr, col_src, aggr);
    gemm_lds<128, false, true><<<grid_g, blk, 0, stream>>>(
        aggr, hB, W3l_hi, W3l_lo, W3r_hi, W3r_lo, b3, nullptr, gsum);

    // Heads (b3 folded into global mean here)
    heads_kernel<<<1, 256, 0, stream>>>(gsum, b3, Pw1, Pb1, Pw2, Pb2,
                                        Vw1, Vb1, Vw2, Vb2, outp,
                                        1.0f / (float)NN);
}

// Round 12
// 365.153 us; speedup vs baseline: 1.6320x; 1.6320x over previous
//
#include <hip/hip_runtime.h>
#include <hip/hip_bf16.h>

#define NN   100000
#define HIDD 128
#define NB   782          // ceil(NN/128) buckets of 128 nodes

typedef __attribute__((ext_vector_type(8))) short bf16x8;
typedef __attribute__((ext_vector_type(4))) float f32x4;

// RNE fp32 -> bf16 bits
__device__ __forceinline__ short bf16_rne(float v) {
    unsigned u = __float_as_uint(v);
    unsigned r = (u + 0x7fffu + ((u >> 16) & 1u)) >> 16;
    return (short)r;
}
__device__ __forceinline__ float bf16_to_f32(short b) {
    return __uint_as_float(((unsigned)(unsigned short)b) << 16);
}
__device__ __forceinline__ float bf16u_to_f32(ushort b) {
    return __uint_as_float(((unsigned)b) << 16);
}
__device__ __forceinline__ unsigned pack2(float a, float b) {
    return ((unsigned)(unsigned short)bf16_rne(a)) |
           (((unsigned)(unsigned short)bf16_rne(b)) << 16);
}

// ---------------------------------------------------------------------------
// Bucketed CSR build. bucket = dst >> 7 (128 nodes per bucket).
// ---------------------------------------------------------------------------
__global__ __launch_bounds__(256)
void bucket_hist(const int* __restrict__ edges, int n_edges,
                 int* __restrict__ bcnt) {
    __shared__ int lh[NB];
    for (int i = threadIdx.x; i < NB; i += 256) lh[i] = 0;
    __syncthreads();
    int stride = gridDim.x * blockDim.x;
    for (int e = blockIdx.x * blockDim.x + threadIdx.x; e < n_edges; e += stride) {
        int d = edges[n_edges + e];
        if ((unsigned)d < NN) atomicAdd(&lh[d >> 7], 1);
    }
    __syncthreads();
    for (int i = threadIdx.x; i < NB; i += 256)
        if (lh[i]) atomicAdd(&bcnt[i], lh[i]);
}

__global__ void scan_bptr(const int* __restrict__ bcnt, int* __restrict__ bptr) {
    __shared__ int lds[1024];
    int t = threadIdx.x;
    lds[t] = (t < NB) ? bcnt[t] : 0;
    __syncthreads();
    for (int off = 1; off < 1024; off <<= 1) {
        int u = (t >= off) ? lds[t - off] : 0;
        __syncthreads();
        lds[t] += u;
        __syncthreads();
    }
    if (t < NB) bptr[t + 1] = lds[t];
    if (t == 0) bptr[0] = 0;
}

// Scatter edges into bucket regions as packed (dst_local<<17 | src).
#define SCAT_CHUNK 2048
__global__ __launch_bounds__(256)
void bucket_scatter(const int* __restrict__ edges, int n_edges,
                    const int* __restrict__ bptr, int* __restrict__ bcur,
                    int* __restrict__ bedges) {
    __shared__ int lh[NB];
    __shared__ int lbase[NB];
    int t = threadIdx.x;
    int base = blockIdx.x * SCAT_CHUNK;
    for (int i = t; i < NB; i += 256) lh[i] = 0;
    __syncthreads();
#pragma unroll
    for (int i = 0; i < SCAT_CHUNK / 256; ++i) {
        int e = base + i * 256 + t;
        if (e < n_edges) {
            int d = edges[n_edges + e];
            if ((unsigned)d < NN) atomicAdd(&lh[d >> 7], 1);
        }
    }
    __syncthreads();
    for (int i = t; i < NB; i += 256) {
        int c = lh[i];
        lbase[i] = (c > 0) ? atomicAdd(&bcur[i], c) : 0;
        lh[i] = 0;   // reuse as cursor
    }
    __syncthreads();
#pragma unroll
    for (int i = 0; i < SCAT_CHUNK / 256; ++i) {
        int e = base + i * 256 + t;
        if (e < n_edges) {
            int s = edges[e];
            int d = edges[n_edges + e];
            if ((unsigned)d < NN && (unsigned)s < NN) {
                int b = d >> 7;
                int off = atomicAdd(&lh[b], 1);
                bedges[bptr[b] + lbase[b] + off] = ((d & 127) << 17) | s;
            }
        }
    }
}

// One block per bucket: local count -> scan -> place. Emits row_ptr + col_src.
__global__ __launch_bounds__(256)
void bucket_csr(const int* __restrict__ bedges, const int* __restrict__ bptr,
                int* __restrict__ row_ptr, int* __restrict__ col_src) {
    __shared__ int lcnt[128];
    __shared__ int lexcl[128];
    int b = blockIdx.x;
    int t = threadIdx.x;
    int beg = bptr[b], end = bptr[b + 1];
    if (t < 128) lcnt[t] = 0;
    __syncthreads();
    for (int e = beg + t; e < end; e += 256)
        atomicAdd(&lcnt[bedges[e] >> 17], 1);
    __syncthreads();
    if (t < 128) lexcl[t] = lcnt[t];
    __syncthreads();
    for (int off = 1; off < 128; off <<= 1) {
        int u = (t < 128 && t >= off) ? lexcl[t - off] : 0;
        __syncthreads();
        if (t < 128) lexcl[t] += u;
        __syncthreads();
    }
    int node0 = b << 7;
    if (t < 128) {
        int excl = lexcl[t] - lcnt[t];   // exclusive scan
        int node = node0 + t;
        if (node < NN) row_ptr[node] = beg + excl;
        lexcl[t] = excl;
        lcnt[t] = 0;                     // reuse as cursor
    }
    if (b == NB - 1 && t == 0) row_ptr[NN] = end;
    __syncthreads();
    for (int e = beg + t; e < end; e += 256) {
        int p = bedges[e];
        int dl = p >> 17, src = p & 0x1FFFF;
        int pos = atomicAdd(&lcnt[dl], 1);
        col_src[beg + lexcl[dl] + pos] = src;
    }
}

// ---------------------------------------------------------------------------
// fp32 -> bf16 conversion (x)
// ---------------------------------------------------------------------------
__global__ void to_bf16(const float* __restrict__ in, ushort* __restrict__ out, int n) {
    int i = (blockIdx.x * blockDim.x + threadIdx.x) * 4;
    if (i + 3 >= n) {
        for (int k = i; k < n; ++k) out[k] = (ushort)bf16_rne(in[k]);
        return;
    }
    float4 v = *(const float4*)&in[i];
    unsigned lo = pack2(v.x, v.y), hi = pack2(v.z, v.w);
    *(uint2*)&out[i] = make_uint2(lo, hi);
}

// ---------------------------------------------------------------------------
// Pull-mode mean aggregation, wide-load form (r10 — near gather ceiling;
// r11 XCD-slicing regressed 3x: sub-line reads amplified fetch, reverted).
// ---------------------------------------------------------------------------
__global__ void aggregate128_bf16(const ushort* __restrict__ h16,
                                  const int* __restrict__ row_ptr,
                                  const int* __restrict__ col_src,
                                  ushort* __restrict__ aggr16, int n_nodes) {
    int node = (int)((blockIdx.x * (size_t)blockDim.x + threadIdx.x) >> 6);
    int lane = threadIdx.x & 63;
    if (node >= n_nodes) return;
    const int g   = lane >> 4;        // neighbor group 0..3
    const int seg = lane & 15;        // 16B segment within row
    int beg = row_ptr[node], end = row_ptr[node + 1];
    float s[8] = {0.f, 0.f, 0.f, 0.f, 0.f, 0.f, 0.f, 0.f};
    int j = beg;
    for (; j + 8 <= end; j += 8) {                 // 2 batches in flight
        int i0 = col_src[j + g];
        int i1 = col_src[j + 4 + g];
        bf16x8 v0 = *(const bf16x8*)&h16[(size_t)i0 * HIDD + seg * 8];
        bf16x8 v1 = *(const bf16x8*)&h16[(size_t)i1 * HIDD + seg * 8];
#pragma unroll
        for (int e = 0; e < 8; ++e)
            s[e] += bf16u_to_f32((ushort)v0[e]) + bf16u_to_f32((ushort)v1[e]);
    }
    for (; j + 4 <= end; j += 4) {
        int i0 = col_src[j + g];
        bf16x8 v0 = *(const bf16x8*)&h16[(size_t)i0 * HIDD + seg * 8];
#pragma unroll
        for (int e = 0; e < 8; ++e) s[e] += bf16u_to_f32((ushort)v0[e]);
    }
    int rem = end - j;
    if (g < rem) {                                 // masked tail, one step
        int i0 = col_src[j + g];
        bf16x8 v0 = *(const bf16x8*)&h16[(size_t)i0 * HIDD + seg * 8];
#pragma unroll
        for (int e = 0; e < 8; ++e) s[e] += bf16u_to_f32((ushort)v0[e]);
    }
    // reduce across the 4 groups
#pragma unroll
    for (int e = 0; e < 8; ++e) {
        s[e] += __shfl_xor(s[e], 16);
        s[e] += __shfl_xor(s[e], 32);
    }
    float inv = (end > beg) ? 1.0f / (float)(end - beg) : 0.0f;
    if (lane < 16) {
        unsigned r0 = pack2(s[0] * inv, s[1] * inv);
        unsigned r1 = pack2(s[2] * inv, s[3] * inv);
        unsigned r2 = pack2(s[4] * inv, s[5] * inv);
        unsigned r3 = pack2(s[6] * inv, s[7] * inv);
        *(uint4*)&aggr16[(size_t)node * HIDD + seg * 8] = make_uint4(r0, r1, r2, r3);
    }
}

// One wave per node; 4 lanes x 16B cover one 64B row; 16 groups =>
// 16 neighbors per load instruction. deg~16 => ~1 batch + masked tail.
__global__ void aggregate32_bf16(const ushort* __restrict__ x16,
                                 const int* __restrict__ row_ptr,
                                 const int* __restrict__ col_src,
                                 ushort* __restrict__ aggr16, int n_nodes) {
    int node = (int)((blockIdx.x * (size_t)blockDim.x + threadIdx.x) >> 6);
    int lane = threadIdx.x & 63;
    if (node >= n_nodes) return;
    const int g   = lane >> 2;        // neighbor group 0..15
    const int seg = lane & 3;         // 16B segment within 64B row
    int beg = row_ptr[node], end = row_ptr[node + 1];
    float s[8] = {0.f, 0.f, 0.f, 0.f, 0.f, 0.f, 0.f, 0.f};
    int j = beg;
    for (; j + 16 <= end; j += 16) {
        int i0 = col_src[j + g];
        bf16x8 v0 = *(const bf16x8*)&x16[(size_t)i0 * 32 + seg * 8];
#pragma unroll
        for (int e = 0; e < 8; ++e) s[e] += bf16u_to_f32((ushort)v0[e]);
    }
    int rem = end - j;
    if (g < rem) {                                 // masked tail (up to 15)
        int i0 = col_src[j + g];
        bf16x8 v0 = *(const bf16x8*)&x16[(size_t)i0 * 32 + seg * 8];
#pragma unroll
        for (int e = 0; e < 8; ++e) s[e] += bf16u_to_f32((ushort)v0[e]);
    }
    // reduce across the 16 groups
#pragma unroll
    for (int e = 0; e < 8; ++e) {
        s[e] += __shfl_xor(s[e], 4);
        s[e] += __shfl_xor(s[e], 8);
        s[e] += __shfl_xor(s[e], 16);
        s[e] += __shfl_xor(s[e], 32);
    }
    float inv = (end > beg) ? 1.0f / (float)(end - beg) : 0.0f;
    if (lane < 4) {
        unsigned r0 = pack2(s[0] * inv, s[1] * inv);
        unsigned r1 = pack2(s[2] * inv, s[3] * inv);
        unsigned r2 = pack2(s[4] * inv, s[5] * inv);
        unsigned r3 = pack2(s[6] * inv, s[7] * inv);
        *(uint4*)&aggr16[(size_t)node * 32 + seg * 8] = make_uint4(r0, r1, r2, r3);
    }
}

// ---------------------------------------------------------------------------
// Weight pre-split: fp32 -> (hi, lo) bf16 planes, all 6 conv matrices.
// ---------------------------------------------------------------------------
__global__ void split_weights(const float* __restrict__ W1l, const float* __restrict__ W1r,
                              const float* __restrict__ W2l, const float* __restrict__ W2r,
                              const float* __restrict__ W3l, const float* __restrict__ W3r,
                              short* __restrict__ whi, short* __restrict__ wlo) {
    int i = blockIdx.x * blockDim.x + threadIdx.x;
    if (i >= 73728) return;
    const float* src; int off;
    if (i < 4096)       { src = W1l; off = 0; }
    else if (i < 8192)  { src = W1r; off = 4096; }
    else if (i < 24576) { src = W2l; off = 8192; }
    else if (i < 40960) { src = W2r; off = 24576; }
    else if (i < 57344) { src = W3l; off = 40960; }
    else                { src = W3r; off = 57344; }
    float v = src[i - off];
    short h = bf16_rne(v);
    float l = v - bf16_to_f32(h);
    whi[i] = h;
    wlo[i] = bf16_rne(l);
}

// ---------------------------------------------------------------------------
// LDS-staged MFMA dual GEMM — 8-wave blocks for 4 waves/SIMD occupancy.
// r9's 256-thr/2-blocks-per-CU gave only 2 waves/SIMD (latency-exposed).
// Now: 512 thr = 8 waves share the same 64KB W-stage; wave = (strip, rowhalf).
// Per iteration a wave does 16 rows: 8 A-loads + 16 ds_read_b128 + 16 MFMA.
// LDS XOR chunk swizzle on write AND read (unchanged). 100000 = 3125*32.
// ---------------------------------------------------------------------------
template <int KA, bool RELU, bool MEAN>
__global__ __launch_bounds__(512, 4)
void gemm_lds(const ushort* __restrict__ inA, const ushort* __restrict__ inB,
              const short* __restrict__ WAhi, const short* __restrict__ WAlo,
              const short* __restrict__ WBhi, const short* __restrict__ WBlo,
              const float* __restrict__ bias,
              ushort* __restrict__ out, float* __restrict__ gsum) {
    constexpr int NCH   = KA / 32;     // k-chunks
    constexpr int NFRAG = 4 * NCH;     // W frags per 16-col strip (2op x NCH x 2pl)
    constexpr int NTILE = NN / 32;     // 3125 row tiles, exact
    __shared__ ushort sW[8192 * NCH];  // 16KB * NCH (64KB at KA=128)

    const int t = threadIdx.x;
    const int wave = t >> 6, lane = t & 63;
    const int lcol = lane & 15;        // B col within strip / A row within tile
    const int koff = lane >> 4;        // which 16B k-chunk of the fragment
    const int half = blockIdx.x & 1;
    const int strip = wave & 3;        // 16-col strip
    const int rhalf = wave >> 2;       // which 16-row half of the 32-row tile
    const int o0 = half * 64 + strip * 16;

    // ---- cooperative W staging into LDS (swizzled) ----
    for (int i = t; i < 1024 * NCH; i += 512) {
        int tile = i >> 6;             // [0, 16*NCH): (strip, frag)
        int w2 = i & 63;
        int c  = w2 >> 2;              // col 0..15
        int kf = w2 & 3;               // chunk 0..3
        int ws = tile / NFRAG;
        int f  = tile % NFRAG;
        int op = f / (NCH * 2);
        int rem = f % (NCH * 2);
        int ch = rem >> 1;
        int pl = rem & 1;
        const short* Wp = op ? (pl ? WBlo : WBhi) : (pl ? WAlo : WAhi);
        int cg = half * 64 + ws * 16 + c;
        bf16x8 v = *(const bf16x8*)&Wp[(size_t)cg * KA + ch * 32 + kf * 8];
        *(bf16x8*)&sW[ws * (2048 * NCH) + f * 512 + c * 32 + ((kf ^ (c & 3)) * 8)] = v;
    }
    __syncthreads();

    const int wbase = strip * (2048 * NCH) + lcol * 32 + ((koff ^ (lcol & 3)) * 8);
    const int lk8 = koff * 8;
    const float bv = MEAN ? 0.f : bias[o0 + lcol];
    const int rg = koff * 4;           // C row-group base
    float csum = 0.f;

    for (int rt = blockIdx.x >> 1; rt < NTILE; rt += (gridDim.x >> 1)) {
        const int r0 = rt * 32 + rhalf * 16;
        // ---- A loads, all issued up front (independent) ----
        bf16x8 a[2][NCH];
#pragma unroll
        for (int op = 0; op < 2; ++op) {
            const ushort* __restrict__ in = op ? inB : inA;
            const ushort* p0 = in + (size_t)(r0 + lcol) * KA + lk8;
#pragma unroll
            for (int ch = 0; ch < NCH; ++ch)
                a[op][ch] = *(const bf16x8*)(p0 + ch * 32);
        }
        f32x4 acc = (f32x4){0.f, 0.f, 0.f, 0.f};
#pragma unroll
        for (int op = 0; op < 2; ++op)
#pragma unroll
            for (int ch = 0; ch < NCH; ++ch)
#pragma unroll
                for (int pl = 0; pl < 2; ++pl) {
                    int f = (op * NCH + ch) * 2 + pl;
                    bf16x8 wf = *(const bf16x8*)&sW[wbase + f * 512];
                    acc = __builtin_amdgcn_mfma_f32_16x16x32_bf16(a[op][ch], wf, acc, 0, 0, 0);
                }
        if (!MEAN) {
            const int o = o0 + lcol;
#pragma unroll
            for (int r = 0; r < 4; ++r) {
                float v0 = acc[r] + bv;
                if (RELU) v0 = fmaxf(v0, 0.f);
                out[(size_t)(r0 + rg + r) * HIDD + o] = (ushort)bf16_rne(v0);
            }
        } else {
            csum += (acc[0] + acc[1]) + (acc[2] + acc[3]);
        }
    }

    if (MEAN) {
        float s = csum;
        s += __shfl_xor(s, 16);
        s += __shfl_xor(s, 32);
        if (lane < 16) atomicAdd(&gsum[o0 + lane], s);
    }
}

// ---------------------------------------------------------------------------
// Heads: g = gsum/N + b3; logits = relu(g@Pw1.T+Pb1)@Pw2.T+Pb2; value likewise.
// ---------------------------------------------------------------------------
__global__ void heads_kernel(const float* __restrict__ gsum,
                             const float* __restrict__ b3,
                             const float* __restrict__ Pw1, const float* __restrict__ Pb1,
                             const float* __restrict__ Pw2, const float* __restrict__ Pb2,
                             const float* __restrict__ Vw1, const float* __restrict__ Vb1,
                             const float* __restrict__ Vw2, const float* __restrict__ Vb2,
                             float* __restrict__ out, float inv_n) {
    __shared__ float g[128], a1[128], v1[128];
    int t = threadIdx.x;
    if (t < 128) g[t] = gsum[t] * inv_n + b3[t];
    __syncthreads();
    if (t < 128) {
        float s = Pb1[t];
        for (int f = 0; f < 128; ++f) s = fmaf(Pw1[t * 128 + f], g[f], s);
        a1[t] = fmaxf(s, 0.f);
    } else {
        int o = t - 128;
        float s = Vb1[o];
        for (int f = 0; f < 128; ++f) s = fmaf(Vw1[o * 128 + f], g[f], s);
        v1[o] = fmaxf(s, 0.f);
    }
    __syncthreads();
    if (t < 6) {
        float s = Pb2[t];
        for (int f = 0; f < 128; ++f) s = fmaf(Pw2[t * 128 + f], a1[f], s);
        out[t] = s;
    }
    if (t == 6) {
        float s = Vb2[0];
        for (int f = 0; f < 128; ++f) s = fmaf(Vw2[f], v1[f], s);
        out[6] = s;
    }
}

// ---------------------------------------------------------------------------
extern "C" void kernel_launch(void* const* d_in, const int* in_sizes, int n_in,
                              void* d_out, int out_size, void* d_ws, size_t ws_size,
                              hipStream_t stream) {
    const float* x    = (const float*)d_in[0];
    const int*   edges = (const int*)d_in[1];
    const float* W1l = (const float*)d_in[2];
    const float* b1  = (const float*)d_in[3];
    const float* W1r = (const float*)d_in[4];
    const float* W2l = (const float*)d_in[5];
    const float* b2  = (const float*)d_in[6];
    const float* W2r = (const float*)d_in[7];
    const float* W3l = (const float*)d_in[8];
    const float* b3  = (const float*)d_in[9];
    const float* W3r = (const float*)d_in[10];
    const float* Pw1 = (const float*)d_in[11];
    const float* Pb1 = (const float*)d_in[12];
    const float* Pw2 = (const float*)d_in[13];
    const float* Pb2 = (const float*)d_in[14];
    const float* Vw1 = (const float*)d_in[15];
    const float* Vb1 = (const float*)d_in[16];
    const float* Vw2 = (const float*)d_in[17];
    const float* Vb2 = (const float*)d_in[18];
    float* outp = (float*)d_out;

    const int E = in_sizes[1] / 2;

    // ---- workspace layout (int offsets, regions 256B-aligned) ----
    int*   ws_i = (int*)d_ws;
    float* ws_f = (float*)d_ws;
    size_t o_bcnt = 0;                 // NB ints   (zeroed)
    size_t o_bcur = 832;               // NB ints   (zeroed)
    size_t o_gsum = 1664;              // 128 f32   (zeroed)
    size_t o_bptr = 1792;              // NB+1
    size_t o_rowp = 2624;              // NN+1
    size_t o_bed  = 102656;            // E packed bucket edges
    size_t o_col  = o_bed + (size_t)E;           // E
    size_t o_whi  = ((o_col + (size_t)E + 63) / 64) * 64;  // 73728 shorts = 36864 ints
    size_t o_wlo  = o_whi + 36864;
    size_t o_x16  = o_wlo + 36864;               // NN*32 bf16 = NN*16 ints
    size_t o_aggr = o_x16 + (size_t)NN * 16;     // NN*128 bf16 = NN*64 ints
    size_t o_hA   = o_aggr + (size_t)NN * 64;
    size_t o_hB   = o_hA + (size_t)NN * 64;

    int*    bcnt    = ws_i + o_bcnt;
    int*    bcur    = ws_i + o_bcur;
    float*  gsum    = ws_f + o_gsum;
    int*    bptr    = ws_i + o_bptr;
    int*    row_ptr = ws_i + o_rowp;
    int*    bedges  = ws_i + o_bed;
    int*    col_src = ws_i + o_col;
    short*  whi     = (short*)(ws_i + o_whi);
    short*  wlo     = (short*)(ws_i + o_wlo);
    ushort* x16     = (ushort*)(ws_i + o_x16);
    ushort* aggr    = (ushort*)(ws_i + o_aggr);
    ushort* hA      = (ushort*)(ws_i + o_hA);
    ushort* hB      = (ushort*)(ws_i + o_hB);

    short* W1l_hi = whi + 0;     short* W1l_lo = wlo + 0;
    short* W1r_hi = whi + 4096;  short* W1r_lo = wlo + 4096;
    short* W2l_hi = whi + 8192;  short* W2l_lo = wlo + 8192;
    short* W2r_hi = whi + 24576; short* W2r_lo = wlo + 24576;
    short* W3l_hi = whi + 40960; short* W3l_lo = wlo + 40960;
    short* W3r_hi = whi + 57344; short* W3r_lo = wlo + 57344;

    // zero bcnt, bcur, gsum
    hipMemsetAsync(d_ws, 0, 1792 * sizeof(int), stream);

    const int TB = 256;
    dim3 blk(TB);
    dim3 blk512(512);

    // independent prep
    to_bf16<<<(NN * 32 / 4 + TB - 1) / TB, blk, 0, stream>>>(x, x16, NN * 32);
    split_weights<<<(73728 + TB - 1) / TB, blk, 0, stream>>>(
        W1l, W1r, W2l, W2r, W3l, W3r, whi, wlo);

    // bucketed CSR build
    bucket_hist<<<256, blk, 0, stream>>>(edges, E, bcnt);
    scan_bptr<<<1, 1024, 0, stream>>>(bcnt, bptr);
    bucket_scatter<<<(E + SCAT_CHUNK - 1) / SCAT_CHUNK, blk, 0, stream>>>(
        edges, E, bptr, bcur, bedges);
    bucket_csr<<<NB, blk, 0, stream>>>(bedges, bptr, row_ptr, col_src);

    dim3 grid_agg((size_t)NN * 64 / TB);   // 25000: one wave per node
    dim3 grid_g(512);                      // 256 blocks per col-half

    // Layer 1 (K=32, relu)
    aggregate32_bf16<<<grid_agg, blk, 0, stream>>>(x16, row_ptr, col_src, aggr, NN);
    gemm_lds<32, true, false><<<grid_g, blk512, 0, stream>>>(
        aggr, x16, W1l_hi, W1l_lo, W1r_hi, W1r_lo, b1, hA, nullptr);

    // Layer 2 (K=128, relu)
    aggregate128_bf16<<<grid_agg, blk, 0, stream>>>(hA, row_ptr, col_src, aggr, NN);
    gemm_lds<128, true, false><<<grid_g, blk512, 0, stream>>>(
        aggr, hA, W2l_hi, W2l_lo, W2r_hi, W2r_lo, b2, hB, nullptr);

    // Layer 3 (K=128, fused column-mean into gsum)
    aggregate128_bf16<<<grid_agg, blk, 0, stream>>>(hB, row_ptr, col_src, aggr, NN);
    gemm_lds<128, false, true><<<grid_g, blk512, 0, stream>>>(
        aggr, hB, W3l_hi, W3l_lo, W3r_hi, W3r_lo, b3, nullptr, gsum);

    // Heads (b3 folded into global mean here)
    heads_kernel<<<1, 256, 0, stream>>>(gsum, b3, Pw1, Pb1, Pw2, Pb2,
                                        Vw1, Vb1, Vw2, Vb2, outp,
                                        1.0f / (float)NN);
}

// Round 13
// 335.246 us; speedup vs baseline: 1.7776x; 1.0892x over previous
//
#include <hip/hip_runtime.h>
#include <hip/hip_bf16.h>

#define NN   100000
#define HIDD 128
#define NB   782          // ceil(NN/128) buckets of 128 nodes

typedef __attribute__((ext_vector_type(8))) short bf16x8;
typedef __attribute__((ext_vector_type(4))) float f32x4;
typedef __attribute__((ext_vector_type(16))) float f32x16;

// RNE fp32 -> bf16 bits
__device__ __forceinline__ short bf16_rne(float v) {
    unsigned u = __float_as_uint(v);
    unsigned r = (u + 0x7fffu + ((u >> 16) & 1u)) >> 16;
    return (short)r;
}
__device__ __forceinline__ float bf16_to_f32(short b) {
    return __uint_as_float(((unsigned)(unsigned short)b) << 16);
}
__device__ __forceinline__ float bf16u_to_f32(ushort b) {
    return __uint_as_float(((unsigned)b) << 16);
}
__device__ __forceinline__ unsigned pack2(float a, float b) {
    return ((unsigned)(unsigned short)bf16_rne(a)) |
           (((unsigned)(unsigned short)bf16_rne(b)) << 16);
}

// ---------------------------------------------------------------------------
// Bucketed CSR build. bucket = dst >> 7 (128 nodes per bucket).
// ---------------------------------------------------------------------------
__global__ __launch_bounds__(256)
void bucket_hist(const int* __restrict__ edges, int n_edges,
                 int* __restrict__ bcnt) {
    __shared__ int lh[NB];
    for (int i = threadIdx.x; i < NB; i += 256) lh[i] = 0;
    __syncthreads();
    int stride = gridDim.x * blockDim.x;
    for (int e = blockIdx.x * blockDim.x + threadIdx.x; e < n_edges; e += stride) {
        int d = edges[n_edges + e];
        if ((unsigned)d < NN) atomicAdd(&lh[d >> 7], 1);
    }
    __syncthreads();
    for (int i = threadIdx.x; i < NB; i += 256)
        if (lh[i]) atomicAdd(&bcnt[i], lh[i]);
}

__global__ void scan_bptr(const int* __restrict__ bcnt, int* __restrict__ bptr) {
    __shared__ int lds[1024];
    int t = threadIdx.x;
    lds[t] = (t < NB) ? bcnt[t] : 0;
    __syncthreads();
    for (int off = 1; off < 1024; off <<= 1) {
        int u = (t >= off) ? lds[t - off] : 0;
        __syncthreads();
        lds[t] += u;
        __syncthreads();
    }
    if (t < NB) bptr[t + 1] = lds[t];
    if (t == 0) bptr[0] = 0;
}

// Scatter edges into bucket regions as packed (dst_local<<17 | src).
#define SCAT_CHUNK 2048
__global__ __launch_bounds__(256)
void bucket_scatter(const int* __restrict__ edges, int n_edges,
                    const int* __restrict__ bptr, int* __restrict__ bcur,
                    int* __restrict__ bedges) {
    __shared__ int lh[NB];
    __shared__ int lbase[NB];
    int t = threadIdx.x;
    int base = blockIdx.x * SCAT_CHUNK;
    for (int i = t; i < NB; i += 256) lh[i] = 0;
    __syncthreads();
#pragma unroll
    for (int i = 0; i < SCAT_CHUNK / 256; ++i) {
        int e = base + i * 256 + t;
        if (e < n_edges) {
            int d = edges[n_edges + e];
            if ((unsigned)d < NN) atomicAdd(&lh[d >> 7], 1);
        }
    }
    __syncthreads();
    for (int i = t; i < NB; i += 256) {
        int c = lh[i];
        lbase[i] = (c > 0) ? atomicAdd(&bcur[i], c) : 0;
        lh[i] = 0;   // reuse as cursor
    }
    __syncthreads();
#pragma unroll
    for (int i = 0; i < SCAT_CHUNK / 256; ++i) {
        int e = base + i * 256 + t;
        if (e < n_edges) {
            int s = edges[e];
            int d = edges[n_edges + e];
            if ((unsigned)d < NN && (unsigned)s < NN) {
                int b = d >> 7;
                int off = atomicAdd(&lh[b], 1);
                bedges[bptr[b] + lbase[b] + off] = ((d & 127) << 17) | s;
            }
        }
    }
}

// One block per bucket: local count -> scan -> place. Emits row_ptr + col_src.
__global__ __launch_bounds__(256)
void bucket_csr(const int* __restrict__ bedges, const int* __restrict__ bptr,
                int* __restrict__ row_ptr, int* __restrict__ col_src) {
    __shared__ int lcnt[128];
    __shared__ int lexcl[128];
    int b = blockIdx.x;
    int t = threadIdx.x;
    int beg = bptr[b], end = bptr[b + 1];
    if (t < 128) lcnt[t] = 0;
    __syncthreads();
    for (int e = beg + t; e < end; e += 256)
        atomicAdd(&lcnt[bedges[e] >> 17], 1);
    __syncthreads();
    if (t < 128) lexcl[t] = lcnt[t];
    __syncthreads();
    for (int off = 1; off < 128; off <<= 1) {
        int u = (t < 128 && t >= off) ? lexcl[t - off] : 0;
        __syncthreads();
        if (t < 128) lexcl[t] += u;
        __syncthreads();
    }
    int node0 = b << 7;
    if (t < 128) {
        int excl = lexcl[t] - lcnt[t];   // exclusive scan
        int node = node0 + t;
        if (node < NN) row_ptr[node] = beg + excl;
        lexcl[t] = excl;
        lcnt[t] = 0;                     // reuse as cursor
    }
    if (b == NB - 1 && t == 0) row_ptr[NN] = end;
    __syncthreads();
    for (int e = beg + t; e < end; e += 256) {
        int p = bedges[e];
        int dl = p >> 17, src = p & 0x1FFFF;
        int pos = atomicAdd(&lcnt[dl], 1);
        col_src[beg + lexcl[dl] + pos] = src;
    }
}

// ---------------------------------------------------------------------------
// fp32 -> bf16 conversion (x)
// ---------------------------------------------------------------------------
__global__ void to_bf16(const float* __restrict__ in, ushort* __restrict__ out, int n) {
    int i = (blockIdx.x * blockDim.x + threadIdx.x) * 4;
    if (i + 3 >= n) {
        for (int k = i; k < n; ++k) out[k] = (ushort)bf16_rne(in[k]);
        return;
    }
    float4 v = *(const float4*)&in[i];
    unsigned lo = pack2(v.x, v.y), hi = pack2(v.z, v.w);
    *(uint2*)&out[i] = make_uint2(lo, hi);
}

// ---------------------------------------------------------------------------
// Pull-mode mean aggregation, wide-load form (r10 — near gather ceiling).
// ---------------------------------------------------------------------------
__global__ void aggregate128_bf16(const ushort* __restrict__ h16,
                                  const int* __restrict__ row_ptr,
                                  const int* __restrict__ col_src,
                                  ushort* __restrict__ aggr16, int n_nodes) {
    int node = (int)((blockIdx.x * (size_t)blockDim.x + threadIdx.x) >> 6);
    int lane = threadIdx.x & 63;
    if (node >= n_nodes) return;
    const int g   = lane >> 4;        // neighbor group 0..3
    const int seg = lane & 15;        // 16B segment within row
    int beg = row_ptr[node], end = row_ptr[node + 1];
    float s[8] = {0.f, 0.f, 0.f, 0.f, 0.f, 0.f, 0.f, 0.f};
    int j = beg;
    for (; j + 8 <= end; j += 8) {                 // 2 batches in flight
        int i0 = col_src[j + g];
        int i1 = col_src[j + 4 + g];
        bf16x8 v0 = *(const bf16x8*)&h16[(size_t)i0 * HIDD + seg * 8];
        bf16x8 v1 = *(const bf16x8*)&h16[(size_t)i1 * HIDD + seg * 8];
#pragma unroll
        for (int e = 0; e < 8; ++e)
            s[e] += bf16u_to_f32((ushort)v0[e]) + bf16u_to_f32((ushort)v1[e]);
    }
    for (; j + 4 <= end; j += 4) {
        int i0 = col_src[j + g];
        bf16x8 v0 = *(const bf16x8*)&h16[(size_t)i0 * HIDD + seg * 8];
#pragma unroll
        for (int e = 0; e < 8; ++e) s[e] += bf16u_to_f32((ushort)v0[e]);
    }
    int rem = end - j;
    if (g < rem) {                                 // masked tail, one step
        int i0 = col_src[j + g];
        bf16x8 v0 = *(const bf16x8*)&h16[(size_t)i0 * HIDD + seg * 8];
#pragma unroll
        for (int e = 0; e < 8; ++e) s[e] += bf16u_to_f32((ushort)v0[e]);
    }
    // reduce across the 4 groups
#pragma unroll
    for (int e = 0; e < 8; ++e) {
        s[e] += __shfl_xor(s[e], 16);
        s[e] += __shfl_xor(s[e], 32);
    }
    float inv = (end > beg) ? 1.0f / (float)(end - beg) : 0.0f;
    if (lane < 16) {
        unsigned r0 = pack2(s[0] * inv, s[1] * inv);
        unsigned r1 = pack2(s[2] * inv, s[3] * inv);
        unsigned r2 = pack2(s[4] * inv, s[5] * inv);
        unsigned r3 = pack2(s[6] * inv, s[7] * inv);
        *(uint4*)&aggr16[(size_t)node * HIDD + seg * 8] = make_uint4(r0, r1, r2, r3);
    }
}

// One wave per node; 4 lanes x 16B cover one 64B row; 16 groups =>
// 16 neighbors per load instruction. deg~16 => ~1 batch + masked tail.
__global__ void aggregate32_bf16(const ushort* __restrict__ x16,
                                 const int* __restrict__ row_ptr,
                                 const int* __restrict__ col_src,
                                 ushort* __restrict__ aggr16, int n_nodes) {
    int node = (int)((blockIdx.x * (size_t)blockDim.x + threadIdx.x) >> 6);
    int lane = threadIdx.x & 63;
    if (node >= n_nodes) return;
    const int g   = lane >> 2;        // neighbor group 0..15
    const int seg = lane & 3;         // 16B segment within 64B row
    int beg = row_ptr[node], end = row_ptr[node + 1];
    float s[8] = {0.f, 0.f, 0.f, 0.f, 0.f, 0.f, 0.f, 0.f};
    int j = beg;
    for (; j + 16 <= end; j += 16) {
        int i0 = col_src[j + g];
        bf16x8 v0 = *(const bf16x8*)&x16[(size_t)i0 * 32 + seg * 8];
#pragma unroll
        for (int e = 0; e < 8; ++e) s[e] += bf16u_to_f32((ushort)v0[e]);
    }
    int rem = end - j;
    if (g < rem) {                                 // masked tail (up to 15)
        int i0 = col_src[j + g];
        bf16x8 v0 = *(const bf16x8*)&x16[(size_t)i0 * 32 + seg * 8];
#pragma unroll
        for (int e = 0; e < 8; ++e) s[e] += bf16u_to_f32((ushort)v0[e]);
    }
    // reduce across the 16 groups
#pragma unroll
    for (int e = 0; e < 8; ++e) {
        s[e] += __shfl_xor(s[e], 4);
        s[e] += __shfl_xor(s[e], 8);
        s[e] += __shfl_xor(s[e], 16);
        s[e] += __shfl_xor(s[e], 32);
    }
    float inv = (end > beg) ? 1.0f / (float)(end - beg) : 0.0f;
    if (lane < 4) {
        unsigned r0 = pack2(s[0] * inv, s[1] * inv);
        unsigned r1 = pack2(s[2] * inv, s[3] * inv);
        unsigned r2 = pack2(s[4] * inv, s[5] * inv);
        unsigned r3 = pack2(s[6] * inv, s[7] * inv);
        *(uint4*)&aggr16[(size_t)node * 32 + seg * 8] = make_uint4(r0, r1, r2, r3);
    }
}

// ---------------------------------------------------------------------------
// Weight pre-split: fp32 -> (hi, lo) bf16 planes, all 6 conv matrices.
// ---------------------------------------------------------------------------
__global__ void split_weights(const float* __restrict__ W1l, const float* __restrict__ W1r,
                              const float* __restrict__ W2l, const float* __restrict__ W2r,
                              const float* __restrict__ W3l, const float* __restrict__ W3r,
                              short* __restrict__ whi, short* __restrict__ wlo) {
    int i = blockIdx.x * blockDim.x + threadIdx.x;
    if (i >= 73728) return;
    const float* src; int off;
    if (i < 4096)       { src = W1l; off = 0; }
    else if (i < 8192)  { src = W1r; off = 4096; }
    else if (i < 24576) { src = W2l; off = 8192; }
    else if (i < 40960) { src = W2r; off = 24576; }
    else if (i < 57344) { src = W3l; off = 40960; }
    else                { src = W3r; off = 57344; }
    float v = src[i - off];
    short h = bf16_rne(v);
    float l = v - bf16_to_f32(h);
    whi[i] = h;
    wlo[i] = bf16_rne(l);
}

// ---------------------------------------------------------------------------
// 32x32x16-MFMA dual GEMM, W in LDS (k-major frags, byte-linear reads ->
// conflict-free), A from global. Half the instruction count of the 16x16
// version: per wave-iteration one 32x32 output tile via 16 A-loads(16B) +
// 32 ds_read_b128 + 32 MFMA (K=256 dual-op, hi+lo planes).
// Block 256thr = 4 waves = 2 col-strips(32) x 2 row-halves; block covers a
// 64-col half (blockIdx&1) x 64 rows/tile. LDS 64KB -> 2 blocks/CU.
// Tail: 100000 % 64 = 32 -> clamp loads, guard stores/MEAN by r0 < NN.
// D layout (m74): col=lane&31, row=(reg&3)+8*(reg>>2)+4*(lane>>5).
// MEAN: per-lane column sums across tiles; shfl_xor(32) + atomics at end.
// ---------------------------------------------------------------------------
template <int KA, bool RELU, bool MEAN>
__global__ __launch_bounds__(256)
void gemm32(const ushort* __restrict__ inA, const ushort* __restrict__ inB,
            const short* __restrict__ WAhi, const short* __restrict__ WAlo,
            const short* __restrict__ WBhi, const short* __restrict__ WBlo,
            const float* __restrict__ bias,
            ushort* __restrict__ out, float* __restrict__ gsum) {
    constexpr int NCH = KA / 16;            // k-chunks of 16
    constexpr int NT  = (NN + 63) / 64;     // 1563 row tiles (last is half)
    __shared__ __align__(16) ushort sW[4096 * NCH];  // 64KB at KA=128

    const int t = threadIdx.x;
    const int wave = t >> 6, lane = t & 63;
    const int half  = blockIdx.x & 1;
    const int strip = wave & 1;             // 32-col strip within the half
    const int rhalf = wave >> 1;            // 32-row half within the 64-row tile
    const int col = lane & 31;
    const int kh  = lane >> 5;              // k-half of the fragment
    const int o0 = half * 64 + strip * 32;

    // ---- stage W (hi+lo, both ops) for this 64-col half; dst is linear ----
    for (int i = t; i < 512 * NCH; i += 256) {
        int st  = i / (256 * NCH);
        int rem = i % (256 * NCH);
        int f   = rem >> 6;                 // (op*NCH+ch)*2+pl
        int w   = rem & 63;
        int wkh = w >> 5, wcol = w & 31;
        int op = f / (NCH * 2);
        int r2 = f % (NCH * 2);
        int ch = r2 >> 1, pl = r2 & 1;
        const short* Wp = op ? (pl ? WBlo : WBhi) : (pl ? WAlo : WAhi);
        bf16x8 v = *(const bf16x8*)&Wp[(size_t)(half * 64 + st * 32 + wcol) * KA
                                       + ch * 16 + wkh * 8];
        *(bf16x8*)&sW[(size_t)i * 8] = v;
    }
    __syncthreads();

    const int sbase = strip * (2048 * NCH) + kh * 256 + col * 8;
    const float bv = MEAN ? 0.f : bias[o0 + col];
    float csum = 0.f;

    for (int rt = blockIdx.x >> 1; rt < NT; rt += (gridDim.x >> 1)) {
        const int r0 = rt * 64 + rhalf * 32;
        const int ar = min(r0 + col, NN - 1);     // clamped load row
        f32x16 acc = {0.f,0.f,0.f,0.f,0.f,0.f,0.f,0.f,
                      0.f,0.f,0.f,0.f,0.f,0.f,0.f,0.f};
#pragma unroll
        for (int op = 0; op < 2; ++op) {
            const ushort* __restrict__ in = op ? inB : inA;
            const ushort* ab = in + (size_t)ar * KA + kh * 8;
            bf16x8 a[NCH];
#pragma unroll
            for (int ch = 0; ch < NCH; ++ch) a[ch] = *(const bf16x8*)(ab + ch * 16);
#pragma unroll
            for (int ch = 0; ch < NCH; ++ch) {
                bf16x8 wh = *(const bf16x8*)&sW[sbase + ((op * NCH + ch) * 2 + 0) * 512];
                acc = __builtin_amdgcn_mfma_f32_32x32x16_bf16(a[ch], wh, acc, 0, 0, 0);
                bf16x8 wl = *(const bf16x8*)&sW[sbase + ((op * NCH + ch) * 2 + 1) * 512];
                acc = __builtin_amdgcn_mfma_f32_32x32x16_bf16(a[ch], wl, acc, 0, 0, 0);
            }
        }
        if (r0 < NN) {                      // whole 32-row group valid or not
            if (!MEAN) {
                const int o = o0 + col;
                const int rb = r0 + 4 * kh;
#pragma unroll
                for (int reg = 0; reg < 16; ++reg) {
                    int r = rb + (reg & 3) + 8 * (reg >> 2);
                    float v = acc[reg] + bv;
                    if (RELU) v = fmaxf(v, 0.f);
                    out[(size_t)r * HIDD + o] = (ushort)bf16_rne(v);
                }
            } else {
#pragma unroll
                for (int reg = 0; reg < 16; ++reg) csum += acc[reg];
            }
        }
    }

    if (MEAN) {
        csum += __shfl_xor(csum, 32);       // combine the two row-subsets
        if (lane < 32) atomicAdd(&gsum[o0 + col], csum);
    }
}

// ---------------------------------------------------------------------------
// Heads: g = gsum/N + b3; logits = relu(g@Pw1.T+Pb1)@Pw2.T+Pb2; value likewise.
// ---------------------------------------------------------------------------
__global__ void heads_kernel(const float* __restrict__ gsum,
                             const float* __restrict__ b3,
                             const float* __restrict__ Pw1, const float* __restrict__ Pb1,
                             const float* __restrict__ Pw2, const float* __restrict__ Pb2,
                             const float* __restrict__ Vw1, const float* __restrict__ Vb1,
                             const float* __restrict__ Vw2, const float* __restrict__ Vb2,
                             float* __restrict__ out, float inv_n) {
    __shared__ float g[128], a1[128], v1[128];
    int t = threadIdx.x;
    if (t < 128) g[t] = gsum[t] * inv_n + b3[t];
    __syncthreads();
    if (t < 128) {
        float s = Pb1[t];
        for (int f = 0; f < 128; ++f) s = fmaf(Pw1[t * 128 + f], g[f], s);
        a1[t] = fmaxf(s, 0.f);
    } else {
        int o = t - 128;
        float s = Vb1[o];
        for (int f = 0; f < 128; ++f) s = fmaf(Vw1[o * 128 + f], g[f], s);
        v1[o] = fmaxf(s, 0.f);
    }
    __syncthreads();
    if (t < 6) {
        float s = Pb2[t];
        for (int f = 0; f < 128; ++f) s = fmaf(Pw2[t * 128 + f], a1[f], s);
        out[t] = s;
    }
    if (t == 6) {
        float s = Vb2[0];
        for (int f = 0; f < 128; ++f) s = fmaf(Vw2[f], v1[f], s);
        out[6] = s;
    }
}

// ---------------------------------------------------------------------------
extern "C" void kernel_launch(void* const* d_in, const int* in_sizes, int n_in,
                              void* d_out, int out_size, void* d_ws, size_t ws_size,
                              hipStream_t stream) {
    const float* x    = (const float*)d_in[0];
    const int*   edges = (const int*)d_in[1];
    const float* W1l = (const float*)d_in[2];
    const float* b1  = (const float*)d_in[3];
    const float* W1r = (const float*)d_in[4];
    const float* W2l = (const float*)d_in[5];
    const float* b2  = (const float*)d_in[6];
    const float* W2r = (const float*)d_in[7];
    const float* W3l = (const float*)d_in[8];
    const float* b3  = (const float*)d_in[9];
    const float* W3r = (const float*)d_in[10];
    const float* Pw1 = (const float*)d_in[11];
    const float* Pb1 = (const float*)d_in[12];
    const float* Pw2 = (const float*)d_in[13];
    const float* Pb2 = (const float*)d_in[14];
    const float* Vw1 = (const float*)d_in[15];
    const float* Vb1 = (const float*)d_in[16];
    const float* Vw2 = (const float*)d_in[17];
    const float* Vb2 = (const float*)d_in[18];
    float* outp = (float*)d_out;

    const int E = in_sizes[1] / 2;

    // ---- workspace layout (int offsets, regions 256B-aligned) ----
    int*   ws_i = (int*)d_ws;
    float* ws_f = (float*)d_ws;
    size_t o_bcnt = 0;                 // NB ints   (zeroed)
    size_t o_bcur = 832;               // NB ints   (zeroed)
    size_t o_gsum = 1664;              // 128 f32   (zeroed)
    size_t o_bptr = 1792;              // NB+1
    size_t o_rowp = 2624;              // NN+1
    size_t o_bed  = 102656;            // E packed bucket edges
    size_t o_col  = o_bed + (size_t)E;           // E
    size_t o_whi  = ((o_col + (size_t)E + 63) / 64) * 64;  // 73728 shorts = 36864 ints
    size_t o_wlo  = o_whi + 36864;
    size_t o_x16  = o_wlo + 36864;               // NN*32 bf16 = NN*16 ints
    size_t o_aggr = o_x16 + (size_t)NN * 16;     // NN*128 bf16 = NN*64 ints
    size_t o_hA   = o_aggr + (size_t)NN * 64;
    size_t o_hB   = o_hA + (size_t)NN * 64;

    int*    bcnt    = ws_i + o_bcnt;
    int*    bcur    = ws_i + o_bcur;
    float*  gsum    = ws_f + o_gsum;
    int*    bptr    = ws_i + o_bptr;
    int*    row_ptr = ws_i + o_rowp;
    int*    bedges  = ws_i + o_bed;
    int*    col_src = ws_i + o_col;
    short*  whi     = (short*)(ws_i + o_whi);
    short*  wlo     = (short*)(ws_i + o_wlo);
    ushort* x16     = (ushort*)(ws_i + o_x16);
    ushort* aggr    = (ushort*)(ws_i + o_aggr);
    ushort* hA      = (ushort*)(ws_i + o_hA);
    ushort* hB      = (ushort*)(ws_i + o_hB);

    short* W1l_hi = whi + 0;     short* W1l_lo = wlo + 0;
    short* W1r_hi = whi + 4096;  short* W1r_lo = wlo + 4096;
    short* W2l_hi = whi + 8192;  short* W2l_lo = wlo + 8192;
    short* W2r_hi = whi + 24576; short* W2r_lo = wlo + 24576;
    short* W3l_hi = whi + 40960; short* W3l_lo = wlo + 40960;
    short* W3r_hi = whi + 57344; short* W3r_lo = wlo + 57344;

    // zero bcnt, bcur, gsum
    hipMemsetAsync(d_ws, 0, 1792 * sizeof(int), stream);

    const int TB = 256;
    dim3 blk(TB);

    // independent prep
    to_bf16<<<(NN * 32 / 4 + TB - 1) / TB, blk, 0, stream>>>(x, x16, NN * 32);
    split_weights<<<(73728 + TB - 1) / TB, blk, 0, stream>>>(
        W1l, W1r, W2l, W2r, W3l, W3r, whi, wlo);

    // bucketed CSR build
    bucket_hist<<<256, blk, 0, stream>>>(edges, E, bcnt);
    scan_bptr<<<1, 1024, 0, stream>>>(bcnt, bptr);
    bucket_scatter<<<(E + SCAT_CHUNK - 1) / SCAT_CHUNK, blk, 0, stream>>>(
        edges, E, bptr, bcur, bedges);
    bucket_csr<<<NB, blk, 0, stream>>>(bedges, bptr, row_ptr, col_src);

    dim3 grid_agg((size_t)NN * 64 / TB);   // 25000: one wave per node
    dim3 grid_g(512);                      // 256 blocks per col-half

    // Layer 1 (K=32, relu)
    aggregate32_bf16<<<grid_agg, blk, 0, stream>>>(x16, row_ptr, col_src, aggr, NN);
    gemm32<32, true, false><<<grid_g, blk, 0, stream>>>(
        aggr, x16, W1l_hi, W1l_lo, W1r_hi, W1r_lo, b1, hA, nullptr);

    // Layer 2 (K=128, relu)
    aggregate128_bf16<<<grid_agg, blk, 0, stream>>>(hA, row_ptr, col_src, aggr, NN);
    gemm32<128, true, false><<<grid_g, blk, 0, stream>>>(
        aggr, hA, W2l_hi, W2l_lo, W2r_hi, W2r_lo, b2, hB, nullptr);

    // Layer 3 (K=128, fused column-mean into gsum)
    aggregate128_bf16<<<grid_agg, blk, 0, stream>>>(hB, row_ptr, col_src, aggr, NN);
    gemm32<128, false, true><<<grid_g, blk, 0, stream>>>(
        aggr, hB, W3l_hi, W3l_lo, W3r_hi, W3r_lo, b3, nullptr, gsum);

    // Heads (b3 folded into global mean here)
    heads_kernel<<<1, 256, 0, stream>>>(gsum, b3, Pw1, Pb1, Pw2, Pb2,
                                        Vw1, Vb1, Vw2, Vb2, outp,
                                        1.0f / (float)NN);
}

// Round 14
// 328.847 us; speedup vs baseline: 1.8122x; 1.0195x over previous
//
#include <hip/hip_runtime.h>
#include <hip/hip_bf16.h>

#define NN   100000
#define HIDD 128
#define NB   782          // ceil(NN/128) buckets of 128 nodes

typedef __attribute__((ext_vector_type(8))) short bf16x8;
typedef __attribute__((ext_vector_type(2))) float f32x2;
typedef __attribute__((ext_vector_type(4))) float f32x4;
typedef __attribute__((ext_vector_type(16))) float f32x16;

// RNE fp32 -> bf16 bits
__device__ __forceinline__ short bf16_rne(float v) {
    unsigned u = __float_as_uint(v);
    unsigned r = (u + 0x7fffu + ((u >> 16) & 1u)) >> 16;
    return (short)r;
}
__device__ __forceinline__ float bf16_to_f32(short b) {
    return __uint_as_float(((unsigned)(unsigned short)b) << 16);
}
__device__ __forceinline__ float bf16u_to_f32(ushort b) {
    return __uint_as_float(((unsigned)b) << 16);
}
__device__ __forceinline__ unsigned pack2(float a, float b) {
    return ((unsigned)(unsigned short)bf16_rne(a)) |
           (((unsigned)(unsigned short)bf16_rne(b)) << 16);
}

// ---------------------------------------------------------------------------
// Bucketed CSR build. bucket = dst >> 7 (128 nodes per bucket).
// ---------------------------------------------------------------------------
__global__ __launch_bounds__(256)
void bucket_hist(const int* __restrict__ edges, int n_edges,
                 int* __restrict__ bcnt) {
    __shared__ int lh[NB];
    for (int i = threadIdx.x; i < NB; i += 256) lh[i] = 0;
    __syncthreads();
    int stride = gridDim.x * blockDim.x;
    for (int e = blockIdx.x * blockDim.x + threadIdx.x; e < n_edges; e += stride) {
        int d = edges[n_edges + e];
        if ((unsigned)d < NN) atomicAdd(&lh[d >> 7], 1);
    }
    __syncthreads();
    for (int i = threadIdx.x; i < NB; i += 256)
        if (lh[i]) atomicAdd(&bcnt[i], lh[i]);
}

__global__ void scan_bptr(const int* __restrict__ bcnt, int* __restrict__ bptr) {
    __shared__ int lds[1024];
    int t = threadIdx.x;
    lds[t] = (t < NB) ? bcnt[t] : 0;
    __syncthreads();
    for (int off = 1; off < 1024; off <<= 1) {
        int u = (t >= off) ? lds[t - off] : 0;
        __syncthreads();
        lds[t] += u;
        __syncthreads();
    }
    if (t < NB) bptr[t + 1] = lds[t];
    if (t == 0) bptr[0] = 0;
}

// Scatter edges into bucket regions as packed (dst_local<<17 | src).
#define SCAT_CHUNK 2048
__global__ __launch_bounds__(256)
void bucket_scatter(const int* __restrict__ edges, int n_edges,
                    const int* __restrict__ bptr, int* __restrict__ bcur,
                    int* __restrict__ bedges) {
    __shared__ int lh[NB];
    __shared__ int lbase[NB];
    int t = threadIdx.x;
    int base = blockIdx.x * SCAT_CHUNK;
    for (int i = t; i < NB; i += 256) lh[i] = 0;
    __syncthreads();
#pragma unroll
    for (int i = 0; i < SCAT_CHUNK / 256; ++i) {
        int e = base + i * 256 + t;
        if (e < n_edges) {
            int d = edges[n_edges + e];
            if ((unsigned)d < NN) atomicAdd(&lh[d >> 7], 1);
        }
    }
    __syncthreads();
    for (int i = t; i < NB; i += 256) {
        int c = lh[i];
        lbase[i] = (c > 0) ? atomicAdd(&bcur[i], c) : 0;
        lh[i] = 0;   // reuse as cursor
    }
    __syncthreads();
#pragma unroll
    for (int i = 0; i < SCAT_CHUNK / 256; ++i) {
        int e = base + i * 256 + t;
        if (e < n_edges) {
            int s = edges[e];
            int d = edges[n_edges + e];
            if ((unsigned)d < NN && (unsigned)s < NN) {
                int b = d >> 7;
                int off = atomicAdd(&lh[b], 1);
                bedges[bptr[b] + lbase[b] + off] = ((d & 127) << 17) | s;
            }
        }
    }
}

// One block per bucket: local count -> scan -> place. Emits row_ptr + col_src.
__global__ __launch_bounds__(256)
void bucket_csr(const int* __restrict__ bedges, const int* __restrict__ bptr,
                int* __restrict__ row_ptr, int* __restrict__ col_src) {
    __shared__ int lcnt[128];
    __shared__ int lexcl[128];
    int b = blockIdx.x;
    int t = threadIdx.x;
    int beg = bptr[b], end = bptr[b + 1];
    if (t < 128) lcnt[t] = 0;
    __syncthreads();
    for (int e = beg + t; e < end; e += 256)
        atomicAdd(&lcnt[bedges[e] >> 17], 1);
    __syncthreads();
    if (t < 128) lexcl[t] = lcnt[t];
    __syncthreads();
    for (int off = 1; off < 128; off <<= 1) {
        int u = (t < 128 && t >= off) ? lexcl[t - off] : 0;
        __syncthreads();
        if (t < 128) lexcl[t] += u;
        __syncthreads();
    }
    int node0 = b << 7;
    if (t < 128) {
        int excl = lexcl[t] - lcnt[t];   // exclusive scan
        int node = node0 + t;
        if (node < NN) row_ptr[node] = beg + excl;
        lexcl[t] = excl;
        lcnt[t] = 0;                     // reuse as cursor
    }
    if (b == NB - 1 && t == 0) row_ptr[NN] = end;
    __syncthreads();
    for (int e = beg + t; e < end; e += 256) {
        int p = bedges[e];
        int dl = p >> 17, src = p & 0x1FFFF;
        int pos = atomicAdd(&lcnt[dl], 1);
        col_src[beg + lexcl[dl] + pos] = src;
    }
}

// ---------------------------------------------------------------------------
// fp32 -> bf16 conversion (x)
// ---------------------------------------------------------------------------
__global__ void to_bf16(const float* __restrict__ in, ushort* __restrict__ out, int n) {
    int i = (blockIdx.x * blockDim.x + threadIdx.x) * 4;
    if (i + 3 >= n) {
        for (int k = i; k < n; ++k) out[k] = (ushort)bf16_rne(in[k]);
        return;
    }
    float4 v = *(const float4*)&in[i];
    unsigned lo = pack2(v.x, v.y), hi = pack2(v.z, v.w);
    *(uint2*)&out[i] = make_uint2(lo, hi);
}

// ---------------------------------------------------------------------------
// bf16 -> fp8 e4m3 copy of h (HW cvt, RNE). One thread = 8 elems.
// ---------------------------------------------------------------------------
__global__ __launch_bounds__(256)
void to_fp8(const ushort* __restrict__ in, unsigned char* __restrict__ out, int n8) {
    int i = blockIdx.x * blockDim.x + threadIdx.x;
    if (i >= n8) return;
    uint4 v = *(const uint4*)&in[(size_t)i * 8];
    float f0 = bf16u_to_f32((ushort)(v.x & 0xFFFF)), f1 = bf16u_to_f32((ushort)(v.x >> 16));
    float f2 = bf16u_to_f32((ushort)(v.y & 0xFFFF)), f3 = bf16u_to_f32((ushort)(v.y >> 16));
    float f4 = bf16u_to_f32((ushort)(v.z & 0xFFFF)), f5 = bf16u_to_f32((ushort)(v.z >> 16));
    float f6 = bf16u_to_f32((ushort)(v.w & 0xFFFF)), f7 = bf16u_to_f32((ushort)(v.w >> 16));
    unsigned w0 = 0, w1 = 0;
    w0 = __builtin_amdgcn_cvt_pk_fp8_f32(f0, f1, w0, false);
    w0 = __builtin_amdgcn_cvt_pk_fp8_f32(f2, f3, w0, true);
    w1 = __builtin_amdgcn_cvt_pk_fp8_f32(f4, f5, w1, false);
    w1 = __builtin_amdgcn_cvt_pk_fp8_f32(f6, f7, w1, true);
    *(uint2*)&out[(size_t)i * 8] = make_uint2(w0, w1);
}

// ---------------------------------------------------------------------------
// fp8 pull-mode mean aggregation: one wave per node, row = 128B.
// 16 lanes x 8B per row; groups g=lane>>4 process neighbors j+g (2 batches
// in flight). Decode via HW cvt_pk_f32_fp8 (4 instrs / 8 values).
// Output aggr stays bf16 (GEMM A-operand format unchanged).
// ---------------------------------------------------------------------------
__device__ __forceinline__ void acc_fp8x8(float* s, uint2 u) {
    f32x2 a = __builtin_amdgcn_cvt_pk_f32_fp8(u.x, false);
    f32x2 b = __builtin_amdgcn_cvt_pk_f32_fp8(u.x, true);
    f32x2 c = __builtin_amdgcn_cvt_pk_f32_fp8(u.y, false);
    f32x2 d = __builtin_amdgcn_cvt_pk_f32_fp8(u.y, true);
    s[0] += a[0]; s[1] += a[1]; s[2] += b[0]; s[3] += b[1];
    s[4] += c[0]; s[5] += c[1]; s[6] += d[0]; s[7] += d[1];
}

__global__ void aggregate128_fp8(const unsigned char* __restrict__ h8,
                                 const int* __restrict__ row_ptr,
                                 const int* __restrict__ col_src,
                                 ushort* __restrict__ aggr16, int n_nodes) {
    int node = (int)((blockIdx.x * (size_t)blockDim.x + threadIdx.x) >> 6);
    int lane = threadIdx.x & 63;
    if (node >= n_nodes) return;
    const int g   = lane >> 4;        // neighbor group 0..3
    const int seg = lane & 15;        // 8B segment within 128B row
    int beg = row_ptr[node], end = row_ptr[node + 1];
    float s[8] = {0.f, 0.f, 0.f, 0.f, 0.f, 0.f, 0.f, 0.f};
    int j = beg;
    for (; j + 8 <= end; j += 8) {                 // 2 batches in flight
        int i0 = col_src[j + g];
        int i1 = col_src[j + 4 + g];
        uint2 u0 = *(const uint2*)&h8[(size_t)i0 * HIDD + seg * 8];
        uint2 u1 = *(const uint2*)&h8[(size_t)i1 * HIDD + seg * 8];
        acc_fp8x8(s, u0);
        acc_fp8x8(s, u1);
    }
    for (; j + 4 <= end; j += 4) {
        int i0 = col_src[j + g];
        uint2 u0 = *(const uint2*)&h8[(size_t)i0 * HIDD + seg * 8];
        acc_fp8x8(s, u0);
    }
    int rem = end - j;
    if (g < rem) {                                 // masked tail, one step
        int i0 = col_src[j + g];
        uint2 u0 = *(const uint2*)&h8[(size_t)i0 * HIDD + seg * 8];
        acc_fp8x8(s, u0);
    }
    // reduce across the 4 groups
#pragma unroll
    for (int e = 0; e < 8; ++e) {
        s[e] += __shfl_xor(s[e], 16);
        s[e] += __shfl_xor(s[e], 32);
    }
    float inv = (end > beg) ? 1.0f / (float)(end - beg) : 0.0f;
    if (lane < 16) {
        unsigned r0 = pack2(s[0] * inv, s[1] * inv);
        unsigned r1 = pack2(s[2] * inv, s[3] * inv);
        unsigned r2 = pack2(s[4] * inv, s[5] * inv);
        unsigned r3 = pack2(s[6] * inv, s[7] * inv);
        *(uint4*)&aggr16[(size_t)node * HIDD + seg * 8] = make_uint4(r0, r1, r2, r3);
    }
}

// One wave per node; 4 lanes x 16B cover one 64B row; 16 groups =>
// 16 neighbors per load instruction. deg~16 => ~1 batch + masked tail.
__global__ void aggregate32_bf16(const ushort* __restrict__ x16,
                                 const int* __restrict__ row_ptr,
                                 const int* __restrict__ col_src,
                                 ushort* __restrict__ aggr16, int n_nodes) {
    int node = (int)((blockIdx.x * (size_t)blockDim.x + threadIdx.x) >> 6);
    int lane = threadIdx.x & 63;
    if (node >= n_nodes) return;
    const int g   = lane >> 2;        // neighbor group 0..15
    const int seg = lane & 3;         // 16B segment within 64B row
    int beg = row_ptr[node], end = row_ptr[node + 1];
    float s[8] = {0.f, 0.f, 0.f, 0.f, 0.f, 0.f, 0.f, 0.f};
    int j = beg;
    for (; j + 16 <= end; j += 16) {
        int i0 = col_src[j + g];
        bf16x8 v0 = *(const bf16x8*)&x16[(size_t)i0 * 32 + seg * 8];
#pragma unroll
        for (int e = 0; e < 8; ++e) s[e] += bf16u_to_f32((ushort)v0[e]);
    }
    int rem = end - j;
    if (g < rem) {                                 // masked tail (up to 15)
        int i0 = col_src[j + g];
        bf16x8 v0 = *(const bf16x8*)&x16[(size_t)i0 * 32 + seg * 8];
#pragma unroll
        for (int e = 0; e < 8; ++e) s[e] += bf16u_to_f32((ushort)v0[e]);
    }
    // reduce across the 16 groups
#pragma unroll
    for (int e = 0; e < 8; ++e) {
        s[e] += __shfl_xor(s[e], 4);
        s[e] += __shfl_xor(s[e], 8);
        s[e] += __shfl_xor(s[e], 16);
        s[e] += __shfl_xor(s[e], 32);
    }
    float inv = (end > beg) ? 1.0f / (float)(end - beg) : 0.0f;
    if (lane < 4) {
        unsigned r0 = pack2(s[0] * inv, s[1] * inv);
        unsigned r1 = pack2(s[2] * inv, s[3] * inv);
        unsigned r2 = pack2(s[4] * inv, s[5] * inv);
        unsigned r3 = pack2(s[6] * inv, s[7] * inv);
        *(uint4*)&aggr16[(size_t)node * 32 + seg * 8] = make_uint4(r0, r1, r2, r3);
    }
}

// ---------------------------------------------------------------------------
// Weight pre-split: fp32 -> (hi, lo) bf16 planes, all 6 conv matrices.
// ---------------------------------------------------------------------------
__global__ void split_weights(const float* __restrict__ W1l, const float* __restrict__ W1r,
                              const float* __restrict__ W2l, const float* __restrict__ W2r,
                              const float* __restrict__ W3l, const float* __restrict__ W3r,
                              short* __restrict__ whi, short* __restrict__ wlo) {
    int i = blockIdx.x * blockDim.x + threadIdx.x;
    if (i >= 73728) return;
    const float* src; int off;
    if (i < 4096)       { src = W1l; off = 0; }
    else if (i < 8192)  { src = W1r; off = 4096; }
    else if (i < 24576) { src = W2l; off = 8192; }
    else if (i < 40960) { src = W2r; off = 24576; }
    else if (i < 57344) { src = W3l; off = 40960; }
    else                { src = W3r; off = 57344; }
    float v = src[i - off];
    short h = bf16_rne(v);
    float l = v - bf16_to_f32(h);
    whi[i] = h;
    wlo[i] = bf16_rne(l);
}

// ---------------------------------------------------------------------------
// 32x32x16-MFMA dual GEMM, W in LDS (k-major frags, byte-linear reads ->
// conflict-free), A from global. (r13 structure — left top-5, unchanged.)
// ---------------------------------------------------------------------------
template <int KA, bool RELU, bool MEAN>
__global__ __launch_bounds__(256)
void gemm32(const ushort* __restrict__ inA, const ushort* __restrict__ inB,
            const short* __restrict__ WAhi, const short* __restrict__ WAlo,
            const short* __restrict__ WBhi, const short* __restrict__ WBlo,
            const float* __restrict__ bias,
            ushort* __restrict__ out, float* __restrict__ gsum) {
    constexpr int NCH = KA / 16;            // k-chunks of 16
    constexpr int NT  = (NN + 63) / 64;     // 1563 row tiles (last is half)
    __shared__ __align__(16) ushort sW[4096 * NCH];  // 64KB at KA=128

    const int t = threadIdx.x;
    const int wave = t >> 6, lane = t & 63;
    const int half  = blockIdx.x & 1;
    const int strip = wave & 1;             // 32-col strip within the half
    const int rhalf = wave >> 1;            // 32-row half within the 64-row tile
    const int col = lane & 31;
    const int kh  = lane >> 5;              // k-half of the fragment
    const int o0 = half * 64 + strip * 32;

    // ---- stage W (hi+lo, both ops) for this 64-col half; dst is linear ----
    for (int i = t; i < 512 * NCH; i += 256) {
        int st  = i / (256 * NCH);
        int rem = i % (256 * NCH);
        int f   = rem >> 6;                 // (op*NCH+ch)*2+pl
        int w   = rem & 63;
        int wkh = w >> 5, wcol = w & 31;
        int op = f / (NCH * 2);
        int r2 = f % (NCH * 2);
        int ch = r2 >> 1, pl = r2 & 1;
        const short* Wp = op ? (pl ? WBlo : WBhi) : (pl ? WAlo : WAhi);
        bf16x8 v = *(const bf16x8*)&Wp[(size_t)(half * 64 + st * 32 + wcol) * KA
                                       + ch * 16 + wkh * 8];
        *(bf16x8*)&sW[(size_t)i * 8] = v;
    }
    __syncthreads();

    const int sbase = strip * (2048 * NCH) + kh * 256 + col * 8;
    const float bv = MEAN ? 0.f : bias[o0 + col];
    float csum = 0.f;

    for (int rt = blockIdx.x >> 1; rt < NT; rt += (gridDim.x >> 1)) {
        const int r0 = rt * 64 + rhalf * 32;
        const int ar = min(r0 + col, NN - 1);     // clamped load row
        f32x16 acc = {0.f,0.f,0.f,0.f,0.f,0.f,0.f,0.f,
                      0.f,0.f,0.f,0.f,0.f,0.f,0.f,0.f};
#pragma unroll
        for (int op = 0; op < 2; ++op) {
            const ushort* __restrict__ in = op ? inB : inA;
            const ushort* ab = in + (size_t)ar * KA + kh * 8;
            bf16x8 a[NCH];
#pragma unroll
            for (int ch = 0; ch < NCH; ++ch) a[ch] = *(const bf16x8*)(ab + ch * 16);
#pragma unroll
            for (int ch = 0; ch < NCH; ++ch) {
                bf16x8 wh = *(const bf16x8*)&sW[sbase + ((op * NCH + ch) * 2 + 0) * 512];
                acc = __builtin_amdgcn_mfma_f32_32x32x16_bf16(a[ch], wh, acc, 0, 0, 0);
                bf16x8 wl = *(const bf16x8*)&sW[sbase + ((op * NCH + ch) * 2 + 1) * 512];
                acc = __builtin_amdgcn_mfma_f32_32x32x16_bf16(a[ch], wl, acc, 0, 0, 0);
            }
        }
        if (r0 < NN) {                      // whole 32-row group valid or not
            if (!MEAN) {
                const int o = o0 + col;
                const int rb = r0 + 4 * kh;
#pragma unroll
                for (int reg = 0; reg < 16; ++reg) {
                    int r = rb + (reg & 3) + 8 * (reg >> 2);
                    float v = acc[reg] + bv;
                    if (RELU) v = fmaxf(v, 0.f);
                    out[(size_t)r * HIDD + o] = (ushort)bf16_rne(v);
                }
            } else {
#pragma unroll
                for (int reg = 0; reg < 16; ++reg) csum += acc[reg];
            }
        }
    }

    if (MEAN) {
        csum += __shfl_xor(csum, 32);       // combine the two row-subsets
        if (lane < 32) atomicAdd(&gsum[o0 + col], csum);
    }
}

// ---------------------------------------------------------------------------
// Heads: g = gsum/N + b3; logits = relu(g@Pw1.T+Pb1)@Pw2.T+Pb2; value likewise.
// ---------------------------------------------------------------------------
__global__ void heads_kernel(const float* __restrict__ gsum,
                             const float* __restrict__ b3,
                             const float* __restrict__ Pw1, const float* __restrict__ Pb1,
                             const float* __restrict__ Pw2, const float* __restrict__ Pb2,
                             const float* __restrict__ Vw1, const float* __restrict__ Vb1,
                             const float* __restrict__ Vw2, const float* __restrict__ Vb2,
                             float* __restrict__ out, float inv_n) {
    __shared__ float g[128], a1[128], v1[128];
    int t = threadIdx.x;
    if (t < 128) g[t] = gsum[t] * inv_n + b3[t];
    __syncthreads();
    if (t < 128) {
        float s = Pb1[t];
        for (int f = 0; f < 128; ++f) s = fmaf(Pw1[t * 128 + f], g[f], s);
        a1[t] = fmaxf(s, 0.f);
    } else {
        int o = t - 128;
        float s = Vb1[o];
        for (int f = 0; f < 128; ++f) s = fmaf(Vw1[o * 128 + f], g[f], s);
        v1[o] = fmaxf(s, 0.f);
    }
    __syncthreads();
    if (t < 6) {
        float s = Pb2[t];
        for (int f = 0; f < 128; ++f) s = fmaf(Pw2[t * 128 + f], a1[f], s);
        out[t] = s;
    }
    if (t == 6) {
        float s = Vb2[0];
        for (int f = 0; f < 128; ++f) s = fmaf(Vw2[f], v1[f], s);
        out[6] = s;
    }
}

// ---------------------------------------------------------------------------
extern "C" void kernel_launch(void* const* d_in, const int* in_sizes, int n_in,
                              void* d_out, int out_size, void* d_ws, size_t ws_size,
                              hipStream_t stream) {
    const float* x    = (const float*)d_in[0];
    const int*   edges = (const int*)d_in[1];
    const float* W1l = (const float*)d_in[2];
    const float* b1  = (const float*)d_in[3];
    const float* W1r = (const float*)d_in[4];
    const float* W2l = (const float*)d_in[5];
    const float* b2  = (const float*)d_in[6];
    const float* W2r = (const float*)d_in[7];
    const float* W3l = (const float*)d_in[8];
    const float* b3  = (const float*)d_in[9];
    const float* W3r = (const float*)d_in[10];
    const float* Pw1 = (const float*)d_in[11];
    const float* Pb1 = (const float*)d_in[12];
    const float* Pw2 = (const float*)d_in[13];
    const float* Pb2 = (const float*)d_in[14];
    const float* Vw1 = (const float*)d_in[15];
    const float* Vb1 = (const float*)d_in[16];
    const float* Vw2 = (const float*)d_in[17];
    const float* Vb2 = (const float*)d_in[18];
    float* outp = (float*)d_out;

    const int E = in_sizes[1] / 2;

    // ---- workspace layout (int offsets, regions 256B-aligned) ----
    int*   ws_i = (int*)d_ws;
    float* ws_f = (float*)d_ws;
    size_t o_bcnt = 0;                 // NB ints   (zeroed)
    size_t o_bcur = 832;               // NB ints   (zeroed)
    size_t o_gsum = 1664;              // 128 f32   (zeroed)
    size_t o_bptr = 1792;              // NB+1
    size_t o_rowp = 2624;              // NN+1
    size_t o_bed  = 102656;            // E packed bucket edges
    size_t o_col  = o_bed + (size_t)E;           // E
    size_t o_whi  = ((o_col + (size_t)E + 63) / 64) * 64;  // 73728 shorts = 36864 ints
    size_t o_wlo  = o_whi + 36864;
    size_t o_x16  = o_wlo + 36864;               // NN*32 bf16 = NN*16 ints
    size_t o_aggr = o_x16 + (size_t)NN * 16;     // NN*128 bf16 = NN*64 ints
    size_t o_hA   = o_aggr + (size_t)NN * 64;
    size_t o_hB   = o_hA + (size_t)NN * 64;
    size_t o_h8   = o_hB + (size_t)NN * 64;      // NN*128 fp8 = NN*32 ints

    int*    bcnt    = ws_i + o_bcnt;
    int*    bcur    = ws_i + o_bcur;
    float*  gsum    = ws_f + o_gsum;
    int*    bptr    = ws_i + o_bptr;
    int*    row_ptr = ws_i + o_rowp;
    int*    bedges  = ws_i + o_bed;
    int*    col_src = ws_i + o_col;
    short*  whi     = (short*)(ws_i + o_whi);
    short*  wlo     = (short*)(ws_i + o_wlo);
    ushort* x16     = (ushort*)(ws_i + o_x16);
    ushort* aggr    = (ushort*)(ws_i + o_aggr);
    ushort* hA      = (ushort*)(ws_i + o_hA);
    ushort* hB      = (ushort*)(ws_i + o_hB);
    unsigned char* h8 = (unsigned char*)(ws_i + o_h8);

    short* W1l_hi = whi + 0;     short* W1l_lo = wlo + 0;
    short* W1r_hi = whi + 4096;  short* W1r_lo = wlo + 4096;
    short* W2l_hi = whi + 8192;  short* W2l_lo = wlo + 8192;
    short* W2r_hi = whi + 24576; short* W2r_lo = wlo + 24576;
    short* W3l_hi = whi + 40960; short* W3l_lo = wlo + 40960;
    short* W3r_hi = whi + 57344; short* W3r_lo = wlo + 57344;

    // zero bcnt, bcur, gsum
    hipMemsetAsync(d_ws, 0, 1792 * sizeof(int), stream);

    const int TB = 256;
    dim3 blk(TB);

    // independent prep
    to_bf16<<<(NN * 32 / 4 + TB - 1) / TB, blk, 0, stream>>>(x, x16, NN * 32);
    split_weights<<<(73728 + TB - 1) / TB, blk, 0, stream>>>(
        W1l, W1r, W2l, W2r, W3l, W3r, whi, wlo);

    // bucketed CSR build
    bucket_hist<<<256, blk, 0, stream>>>(edges, E, bcnt);
    scan_bptr<<<1, 1024, 0, stream>>>(bcnt, bptr);
    bucket_scatter<<<(E + SCAT_CHUNK - 1) / SCAT_CHUNK, blk, 0, stream>>>(
        edges, E, bptr, bcur, bedges);
    bucket_csr<<<NB, blk, 0, stream>>>(bedges, bptr, row_ptr, col_src);

    dim3 grid_agg((size_t)NN * 64 / TB);   // 25000: one wave per node
    dim3 grid_f8((NN * 16 + TB - 1) / TB); // NN*128/8 groups
    dim3 grid_g(512);                      // 256 blocks per col-half

    // Layer 1 (K=32, relu)
    aggregate32_bf16<<<grid_agg, blk, 0, stream>>>(x16, row_ptr, col_src, aggr, NN);
    gemm32<32, true, false><<<grid_g, blk, 0, stream>>>(
        aggr, x16, W1l_hi, W1l_lo, W1r_hi, W1r_lo, b1, hA, nullptr);

    // Layer 2 (K=128, relu): gather hA in fp8
    to_fp8<<<grid_f8, blk, 0, stream>>>(hA, h8, NN * 16);
    aggregate128_fp8<<<grid_agg, blk, 0, stream>>>(h8, row_ptr, col_src, aggr, NN);
    gemm32<128, true, false><<<grid_g, blk, 0, stream>>>(
        aggr, hA, W2l_hi, W2l_lo, W2r_hi, W2r_lo, b2, hB, nullptr);

    // Layer 3 (K=128, fused column-mean into gsum): gather hB in fp8
    to_fp8<<<grid_f8, blk, 0, stream>>>(hB, h8, NN * 16);
    aggregate128_fp8<<<grid_agg, blk, 0, stream>>>(h8, row_ptr, col_src, aggr, NN);
    gemm32<128, false, true><<<grid_g, blk, 0, stream>>>(
        aggr, hB, W3l_hi, W3l_lo, W3r_hi, W3r_lo, b3, nullptr, gsum);

    // Heads (b3 folded into global mean here)
    heads_kernel<<<1, 256, 0, stream>>>(gsum, b3, Pw1, Pb1, Pw2, Pb2,
                                        Vw1, Vb1, Vw2, Vb2, outp,
                                        1.0f / (float)NN);
}

// Round 15
// 316.128 us; speedup vs baseline: 1.8851x; 1.0402x over previous
//
#include <hip/hip_runtime.h>
#include <hip/hip_bf16.h>

#define NN   100000
#define HIDD 128
#define NBC  196          // ceil(NN/512) coarse buckets of 512 nodes

typedef __attribute__((ext_vector_type(8))) short bf16x8;
typedef __attribute__((ext_vector_type(2))) float f32x2;
typedef __attribute__((ext_vector_type(4))) float f32x4;
typedef __attribute__((ext_vector_type(16))) float f32x16;

// RNE fp32 -> bf16 bits
__device__ __forceinline__ short bf16_rne(float v) {
    unsigned u = __float_as_uint(v);
    unsigned r = (u + 0x7fffu + ((u >> 16) & 1u)) >> 16;
    return (short)r;
}
__device__ __forceinline__ float bf16_to_f32(short b) {
    return __uint_as_float(((unsigned)(unsigned short)b) << 16);
}
__device__ __forceinline__ float bf16u_to_f32(ushort b) {
    return __uint_as_float(((unsigned)b) << 16);
}
__device__ __forceinline__ unsigned pack2(float a, float b) {
    return ((unsigned)(unsigned short)bf16_rne(a)) |
           (((unsigned)(unsigned short)bf16_rne(b)) << 16);
}

// ---------------------------------------------------------------------------
// Bucketed CSR build. bucket = dst >> 9 (512 nodes per bucket).
// r14: 782 fine buckets gave ~2.6 edges/bucket/block in the scatter ->
// 7x write amplification (WRITE_SIZE 43MB for 6.4MB payload). Coarse 512-node
// buckets + 4096-edge chunks give ~21-edge (84B) runs -> ~1.5x amplification.
// ---------------------------------------------------------------------------
__global__ __launch_bounds__(256)
void bucket_hist(const int* __restrict__ edges, int n_edges,
                 int* __restrict__ bcnt) {
    __shared__ int lh[NBC];
    for (int i = threadIdx.x; i < NBC; i += 256) lh[i] = 0;
    __syncthreads();
    int stride = gridDim.x * blockDim.x;
    for (int e = blockIdx.x * blockDim.x + threadIdx.x; e < n_edges; e += stride) {
        int d = edges[n_edges + e];
        if ((unsigned)d < NN) atomicAdd(&lh[d >> 9], 1);
    }
    __syncthreads();
    for (int i = threadIdx.x; i < NBC; i += 256)
        if (lh[i]) atomicAdd(&bcnt[i], lh[i]);
}

__global__ void scan_bptr(const int* __restrict__ bcnt, int* __restrict__ bptr) {
    __shared__ int lds[256];
    int t = threadIdx.x;
    lds[t] = (t < NBC) ? bcnt[t] : 0;
    __syncthreads();
    for (int off = 1; off < 256; off <<= 1) {
        int u = (t >= off) ? lds[t - off] : 0;
        __syncthreads();
        lds[t] += u;
        __syncthreads();
    }
    if (t < NBC) bptr[t + 1] = lds[t];
    if (t == 0) bptr[0] = 0;
}

// Scatter edges into bucket regions as packed (dst_local<<17 | src).
#define SCAT_CHUNK 4096
__global__ __launch_bounds__(256)
void bucket_scatter(const int* __restrict__ edges, int n_edges,
                    const int* __restrict__ bptr, int* __restrict__ bcur,
                    int* __restrict__ bedges) {
    __shared__ int lh[NBC];
    __shared__ int lbase[NBC];
    int t = threadIdx.x;
    int base = blockIdx.x * SCAT_CHUNK;
    for (int i = t; i < NBC; i += 256) lh[i] = 0;
    __syncthreads();
#pragma unroll
    for (int i = 0; i < SCAT_CHUNK / 256; ++i) {
        int e = base + i * 256 + t;
        if (e < n_edges) {
            int d = edges[n_edges + e];
            if ((unsigned)d < NN) atomicAdd(&lh[d >> 9], 1);
        }
    }
    __syncthreads();
    for (int i = t; i < NBC; i += 256) {
        int c = lh[i];
        lbase[i] = (c > 0) ? atomicAdd(&bcur[i], c) : 0;
        lh[i] = 0;   // reuse as cursor
    }
    __syncthreads();
#pragma unroll
    for (int i = 0; i < SCAT_CHUNK / 256; ++i) {
        int e = base + i * 256 + t;
        if (e < n_edges) {
            int s = edges[e];
            int d = edges[n_edges + e];
            if ((unsigned)d < NN && (unsigned)s < NN) {
                int b = d >> 9;
                int off = atomicAdd(&lh[b], 1);
                bedges[bptr[b] + lbase[b] + off] = ((d & 511) << 17) | s;
            }
        }
    }
}

// One block per 512-node bucket: count -> pairwise scan -> place.
__global__ __launch_bounds__(256)
void bucket_csr512(const int* __restrict__ bedges, const int* __restrict__ bptr,
                   int* __restrict__ row_ptr, int* __restrict__ col_src) {
    __shared__ int lcnt[512];
    __shared__ int lsum[256];
    __shared__ int lexcl[512];
    int b = blockIdx.x;
    int t = threadIdx.x;
    int beg = bptr[b], end = bptr[b + 1];
    lcnt[t] = 0; lcnt[t + 256] = 0;
    __syncthreads();
    for (int e = beg + t; e < end; e += 256)
        atomicAdd(&lcnt[bedges[e] >> 17], 1);
    __syncthreads();
    int a0 = lcnt[2 * t], a1 = lcnt[2 * t + 1];
    lsum[t] = a0 + a1;
    __syncthreads();
    for (int off = 1; off < 256; off <<= 1) {
        int u = (t >= off) ? lsum[t - off] : 0;
        __syncthreads();
        lsum[t] += u;
        __syncthreads();
    }
    int pairExcl = lsum[t] - (a0 + a1);     // exclusive prefix of element 2t
    lexcl[2 * t]     = pairExcl;
    lexcl[2 * t + 1] = pairExcl + a0;
    int node0 = b << 9;
    int n0 = node0 + 2 * t, n1 = node0 + 2 * t + 1;
    if (n0 < NN) row_ptr[n0] = beg + pairExcl;
    if (n1 < NN) row_ptr[n1] = beg + pairExcl + a0;
    lcnt[2 * t] = 0; lcnt[2 * t + 1] = 0;   // reuse as cursors
    if (b == NBC - 1 && t == 0) row_ptr[NN] = end;
    __syncthreads();
    for (int e = beg + t; e < end; e += 256) {
        int p = bedges[e];
        int dl = p >> 17, src = p & 0x1FFFF;
        int pos = atomicAdd(&lcnt[dl], 1);
        col_src[beg + lexcl[dl] + pos] = src;
    }
}

// ---------------------------------------------------------------------------
// fp32 -> bf16 conversion (x)
// ---------------------------------------------------------------------------
__global__ void to_bf16(const float* __restrict__ in, ushort* __restrict__ out, int n) {
    int i = (blockIdx.x * blockDim.x + threadIdx.x) * 4;
    if (i + 3 >= n) {
        for (int k = i; k < n; ++k) out[k] = (ushort)bf16_rne(in[k]);
        return;
    }
    float4 v = *(const float4*)&in[i];
    unsigned lo = pack2(v.x, v.y), hi = pack2(v.z, v.w);
    *(uint2*)&out[i] = make_uint2(lo, hi);
}

// ---------------------------------------------------------------------------
// bf16 -> fp8 e4m3 copy of h (HW cvt, RNE). One thread = 8 elems.
// ---------------------------------------------------------------------------
__global__ __launch_bounds__(256)
void to_fp8(const ushort* __restrict__ in, unsigned char* __restrict__ out, int n8) {
    int i = blockIdx.x * blockDim.x + threadIdx.x;
    if (i >= n8) return;
    uint4 v = *(const uint4*)&in[(size_t)i * 8];
    float f0 = bf16u_to_f32((ushort)(v.x & 0xFFFF)), f1 = bf16u_to_f32((ushort)(v.x >> 16));
    float f2 = bf16u_to_f32((ushort)(v.y & 0xFFFF)), f3 = bf16u_to_f32((ushort)(v.y >> 16));
    float f4 = bf16u_to_f32((ushort)(v.z & 0xFFFF)), f5 = bf16u_to_f32((ushort)(v.z >> 16));
    float f6 = bf16u_to_f32((ushort)(v.w & 0xFFFF)), f7 = bf16u_to_f32((ushort)(v.w >> 16));
    unsigned w0 = 0, w1 = 0;
    w0 = __builtin_amdgcn_cvt_pk_fp8_f32(f0, f1, w0, false);
    w0 = __builtin_amdgcn_cvt_pk_fp8_f32(f2, f3, w0, true);
    w1 = __builtin_amdgcn_cvt_pk_fp8_f32(f4, f5, w1, false);
    w1 = __builtin_amdgcn_cvt_pk_fp8_f32(f6, f7, w1, true);
    *(uint2*)&out[(size_t)i * 8] = make_uint2(w0, w1);
}

// ---------------------------------------------------------------------------
// fp8 pull-mode mean aggregation: one wave per node, row = 128B.
// ---------------------------------------------------------------------------
__device__ __forceinline__ void acc_fp8x8(float* s, uint2 u) {
    f32x2 a = __builtin_amdgcn_cvt_pk_f32_fp8(u.x, false);
    f32x2 b = __builtin_amdgcn_cvt_pk_f32_fp8(u.x, true);
    f32x2 c = __builtin_amdgcn_cvt_pk_f32_fp8(u.y, false);
    f32x2 d = __builtin_amdgcn_cvt_pk_f32_fp8(u.y, true);
    s[0] += a[0]; s[1] += a[1]; s[2] += b[0]; s[3] += b[1];
    s[4] += c[0]; s[5] += c[1]; s[6] += d[0]; s[7] += d[1];
}

__global__ void aggregate128_fp8(const unsigned char* __restrict__ h8,
                                 const int* __restrict__ row_ptr,
                                 const int* __restrict__ col_src,
                                 ushort* __restrict__ aggr16, int n_nodes) {
    int node = (int)((blockIdx.x * (size_t)blockDim.x + threadIdx.x) >> 6);
    int lane = threadIdx.x & 63;
    if (node >= n_nodes) return;
    const int g   = lane >> 4;        // neighbor group 0..3
    const int seg = lane & 15;        // 8B segment within 128B row
    int beg = row_ptr[node], end = row_ptr[node + 1];
    float s[8] = {0.f, 0.f, 0.f, 0.f, 0.f, 0.f, 0.f, 0.f};
    int j = beg;
    for (; j + 8 <= end; j += 8) {                 // 2 batches in flight
        int i0 = col_src[j + g];
        int i1 = col_src[j + 4 + g];
        uint2 u0 = *(const uint2*)&h8[(size_t)i0 * HIDD + seg * 8];
        uint2 u1 = *(const uint2*)&h8[(size_t)i1 * HIDD + seg * 8];
        acc_fp8x8(s, u0);
        acc_fp8x8(s, u1);
    }
    for (; j + 4 <= end; j += 4) {
        int i0 = col_src[j + g];
        uint2 u0 = *(const uint2*)&h8[(size_t)i0 * HIDD + seg * 8];
        acc_fp8x8(s, u0);
    }
    int rem = end - j;
    if (g < rem) {                                 // masked tail, one step
        int i0 = col_src[j + g];
        uint2 u0 = *(const uint2*)&h8[(size_t)i0 * HIDD + seg * 8];
        acc_fp8x8(s, u0);
    }
    // reduce across the 4 groups
#pragma unroll
    for (int e = 0; e < 8; ++e) {
        s[e] += __shfl_xor(s[e], 16);
        s[e] += __shfl_xor(s[e], 32);
    }
    float inv = (end > beg) ? 1.0f / (float)(end - beg) : 0.0f;
    if (lane < 16) {
        unsigned r0 = pack2(s[0] * inv, s[1] * inv);
        unsigned r1 = pack2(s[2] * inv, s[3] * inv);
        unsigned r2 = pack2(s[4] * inv, s[5] * inv);
        unsigned r3 = pack2(s[6] * inv, s[7] * inv);
        *(uint4*)&aggr16[(size_t)node * HIDD + seg * 8] = make_uint4(r0, r1, r2, r3);
    }
}

// One wave per node; 4 lanes x 16B cover one 64B row; 16 groups =>
// 16 neighbors per load instruction. deg~16 => ~1 batch + masked tail.
__global__ void aggregate32_bf16(const ushort* __restrict__ x16,
                                 const int* __restrict__ row_ptr,
                                 const int* __restrict__ col_src,
                                 ushort* __restrict__ aggr16, int n_nodes) {
    int node = (int)((blockIdx.x * (size_t)blockDim.x + threadIdx.x) >> 6);
    int lane = threadIdx.x & 63;
    if (node >= n_nodes) return;
    const int g   = lane >> 2;        // neighbor group 0..15
    const int seg = lane & 3;         // 16B segment within 64B row
    int beg = row_ptr[node], end = row_ptr[node + 1];
    float s[8] = {0.f, 0.f, 0.f, 0.f, 0.f, 0.f, 0.f, 0.f};
    int j = beg;
    for (; j + 16 <= end; j += 16) {
        int i0 = col_src[j + g];
        bf16x8 v0 = *(const bf16x8*)&x16[(size_t)i0 * 32 + seg * 8];
#pragma unroll
        for (int e = 0; e < 8; ++e) s[e] += bf16u_to_f32((ushort)v0[e]);
    }
    int rem = end - j;
    if (g < rem) {                                 // masked tail (up to 15)
        int i0 = col_src[j + g];
        bf16x8 v0 = *(const bf16x8*)&x16[(size_t)i0 * 32 + seg * 8];
#pragma unroll
        for (int e = 0; e < 8; ++e) s[e] += bf16u_to_f32((ushort)v0[e]);
    }
    // reduce across the 16 groups
#pragma unroll
    for (int e = 0; e < 8; ++e) {
        s[e] += __shfl_xor(s[e], 4);
        s[e] += __shfl_xor(s[e], 8);
        s[e] += __shfl_xor(s[e], 16);
        s[e] += __shfl_xor(s[e], 32);
    }
    float inv = (end > beg) ? 1.0f / (float)(end - beg) : 0.0f;
    if (lane < 4) {
        unsigned r0 = pack2(s[0] * inv, s[1] * inv);
        unsigned r1 = pack2(s[2] * inv, s[3] * inv);
        unsigned r2 = pack2(s[4] * inv, s[5] * inv);
        unsigned r3 = pack2(s[6] * inv, s[7] * inv);
        *(uint4*)&aggr16[(size_t)node * 32 + seg * 8] = make_uint4(r0, r1, r2, r3);
    }
}

// ---------------------------------------------------------------------------
// Weight pre-split: fp32 -> (hi, lo) bf16 planes, all 6 conv matrices.
// ---------------------------------------------------------------------------
__global__ void split_weights(const float* __restrict__ W1l, const float* __restrict__ W1r,
                              const float* __restrict__ W2l, const float* __restrict__ W2r,
                              const float* __restrict__ W3l, const float* __restrict__ W3r,
                              short* __restrict__ whi, short* __restrict__ wlo) {
    int i = blockIdx.x * blockDim.x + threadIdx.x;
    if (i >= 73728) return;
    const float* src; int off;
    if (i < 4096)       { src = W1l; off = 0; }
    else if (i < 8192)  { src = W1r; off = 4096; }
    else if (i < 24576) { src = W2l; off = 8192; }
    else if (i < 40960) { src = W2r; off = 24576; }
    else if (i < 57344) { src = W3l; off = 40960; }
    else                { src = W3r; off = 57344; }
    float v = src[i - off];
    short h = bf16_rne(v);
    float l = v - bf16_to_f32(h);
    whi[i] = h;
    wlo[i] = bf16_rne(l);
}

// ---------------------------------------------------------------------------
// 32x32x16-MFMA dual GEMM, W in LDS (k-major frags, byte-linear reads ->
// conflict-free), A from global. (r13 structure — left top-5, unchanged.)
// ---------------------------------------------------------------------------
template <int KA, bool RELU, bool MEAN>
__global__ __launch_bounds__(256)
void gemm32(const ushort* __restrict__ inA, const ushort* __restrict__ inB,
            const short* __restrict__ WAhi, const short* __restrict__ WAlo,
            const short* __restrict__ WBhi, const short* __restrict__ WBlo,
            const float* __restrict__ bias,
            ushort* __restrict__ out, float* __restrict__ gsum) {
    constexpr int NCH = KA / 16;            // k-chunks of 16
    constexpr int NT  = (NN + 63) / 64;     // 1563 row tiles (last is half)
    __shared__ __align__(16) ushort sW[4096 * NCH];  // 64KB at KA=128

    const int t = threadIdx.x;
    const int wave = t >> 6, lane = t & 63;
    const int half  = blockIdx.x & 1;
    const int strip = wave & 1;             // 32-col strip within the half
    const int rhalf = wave >> 1;            // 32-row half within the 64-row tile
    const int col = lane & 31;
    const int kh  = lane >> 5;              // k-half of the fragment
    const int o0 = half * 64 + strip * 32;

    // ---- stage W (hi+lo, both ops) for this 64-col half; dst is linear ----
    for (int i = t; i < 512 * NCH; i += 256) {
        int st  = i / (256 * NCH);
        int rem = i % (256 * NCH);
        int f   = rem >> 6;                 // (op*NCH+ch)*2+pl
        int w   = rem & 63;
        int wkh = w >> 5, wcol = w & 31;
        int op = f / (NCH * 2);
        int r2 = f % (NCH * 2);
        int ch = r2 >> 1, pl = r2 & 1;
        const short* Wp = op ? (pl ? WBlo : WBhi) : (pl ? WAlo : WAhi);
        bf16x8 v = *(const bf16x8*)&Wp[(size_t)(half * 64 + st * 32 + wcol) * KA
                                       + ch * 16 + wkh * 8];
        *(bf16x8*)&sW[(size_t)i * 8] = v;
    }
    __syncthreads();

    const int sbase = strip * (2048 * NCH) + kh * 256 + col * 8;
    const float bv = MEAN ? 0.f : bias[o0 + col];
    float csum = 0.f;

    for (int rt = blockIdx.x >> 1; rt < NT; rt += (gridDim.x >> 1)) {
        const int r0 = rt * 64 + rhalf * 32;
        const int ar = min(r0 + col, NN - 1);     // clamped load row
        f32x16 acc = {0.f,0.f,0.f,0.f,0.f,0.f,0.f,0.f,
                      0.f,0.f,0.f,0.f,0.f,0.f,0.f,0.f};
#pragma unroll
        for (int op = 0; op < 2; ++op) {
            const ushort* __restrict__ in = op ? inB : inA;
            const ushort* ab = in + (size_t)ar * KA + kh * 8;
            bf16x8 a[NCH];
#pragma unroll
            for (int ch = 0; ch < NCH; ++ch) a[ch] = *(const bf16x8*)(ab + ch * 16);
#pragma unroll
            for (int ch = 0; ch < NCH; ++ch) {
                bf16x8 wh = *(const bf16x8*)&sW[sbase + ((op * NCH + ch) * 2 + 0) * 512];
                acc = __builtin_amdgcn_mfma_f32_32x32x16_bf16(a[ch], wh, acc, 0, 0, 0);
                bf16x8 wl = *(const bf16x8*)&sW[sbase + ((op * NCH + ch) * 2 + 1) * 512];
                acc = __builtin_amdgcn_mfma_f32_32x32x16_bf16(a[ch], wl, acc, 0, 0, 0);
            }
        }
        if (r0 < NN) {                      // whole 32-row group valid or not
            if (!MEAN) {
                const int o = o0 + col;
                const int rb = r0 + 4 * kh;
#pragma unroll
                for (int reg = 0; reg < 16; ++reg) {
                    int r = rb + (reg & 3) + 8 * (reg >> 2);
                    float v = acc[reg] + bv;
                    if (RELU) v = fmaxf(v, 0.f);
                    out[(size_t)r * HIDD + o] = (ushort)bf16_rne(v);
                }
            } else {
#pragma unroll
                for (int reg = 0; reg < 16; ++reg) csum += acc[reg];
            }
        }
    }

    if (MEAN) {
        csum += __shfl_xor(csum, 32);       // combine the two row-subsets
        if (lane < 32) atomicAdd(&gsum[o0 + col], csum);
    }
}

// ---------------------------------------------------------------------------
// Heads: g = gsum/N + b3; logits = relu(g@Pw1.T+Pb1)@Pw2.T+Pb2; value likewise.
// ---------------------------------------------------------------------------
__global__ void heads_kernel(const float* __restrict__ gsum,
                             const float* __restrict__ b3,
                             const float* __restrict__ Pw1, const float* __restrict__ Pb1,
                             const float* __restrict__ Pw2, const float* __restrict__ Pb2,
                             const float* __restrict__ Vw1, const float* __restrict__ Vb1,
                             const float* __restrict__ Vw2, const float* __restrict__ Vb2,
                             float* __restrict__ out, float inv_n) {
    __shared__ float g[128], a1[128], v1[128];
    int t = threadIdx.x;
    if (t < 128) g[t] = gsum[t] * inv_n + b3[t];
    __syncthreads();
    if (t < 128) {
        float s = Pb1[t];
        for (int f = 0; f < 128; ++f) s = fmaf(Pw1[t * 128 + f], g[f], s);
        a1[t] = fmaxf(s, 0.f);
    } else {
        int o = t - 128;
        float s = Vb1[o];
        for (int f = 0; f < 128; ++f) s = fmaf(Vw1[o * 128 + f], g[f], s);
        v1[o] = fmaxf(s, 0.f);
    }
    __syncthreads();
    if (t < 6) {
        float s = Pb2[t];
        for (int f = 0; f < 128; ++f) s = fmaf(Pw2[t * 128 + f], a1[f], s);
        out[t] = s;
    }
    if (t == 6) {
        float s = Vb2[0];
        for (int f = 0; f < 128; ++f) s = fmaf(Vw2[f], v1[f], s);
        out[6] = s;
    }
}

// ---------------------------------------------------------------------------
extern "C" void kernel_launch(void* const* d_in, const int* in_sizes, int n_in,
                              void* d_out, int out_size, void* d_ws, size_t ws_size,
                              hipStream_t stream) {
    const float* x    = (const float*)d_in[0];
    const int*   edges = (const int*)d_in[1];
    const float* W1l = (const float*)d_in[2];
    const float* b1  = (const float*)d_in[3];
    const float* W1r = (const float*)d_in[4];
    const float* W2l = (const float*)d_in[5];
    const float* b2  = (const float*)d_in[6];
    const float* W2r = (const float*)d_in[7];
    const float* W3l = (const float*)d_in[8];
    const float* b3  = (const float*)d_in[9];
    const float* W3r = (const float*)d_in[10];
    const float* Pw1 = (const float*)d_in[11];
    const float* Pb1 = (const float*)d_in[12];
    const float* Pw2 = (const float*)d_in[13];
    const float* Pb2 = (const float*)d_in[14];
    const float* Vw1 = (const float*)d_in[15];
    const float* Vb1 = (const float*)d_in[16];
    const float* Vw2 = (const float*)d_in[17];
    const float* Vb2 = (const float*)d_in[18];
    float* outp = (float*)d_out;

    const int E = in_sizes[1] / 2;

    // ---- workspace layout (int offsets, regions 256B-aligned) ----
    int*   ws_i = (int*)d_ws;
    float* ws_f = (float*)d_ws;
    size_t o_bcnt = 0;                 // NBC ints  (zeroed)
    size_t o_bcur = 256;               // NBC ints  (zeroed)
    size_t o_gsum = 512;               // 128 f32   (zeroed)
    size_t o_bptr = 640;               // NBC+1
    size_t o_rowp = 896;               // NN+1
    size_t o_bed  = 100928;            // E packed bucket edges
    size_t o_col  = o_bed + (size_t)E;           // E
    size_t o_whi  = ((o_col + (size_t)E + 63) / 64) * 64;  // 73728 shorts = 36864 ints
    size_t o_wlo  = o_whi + 36864;
    size_t o_x16  = o_wlo + 36864;               // NN*32 bf16 = NN*16 ints
    size_t o_aggr = o_x16 + (size_t)NN * 16;     // NN*128 bf16 = NN*64 ints
    size_t o_hA   = o_aggr + (size_t)NN * 64;
    size_t o_hB   = o_hA + (size_t)NN * 64;
    size_t o_h8   = o_hB + (size_t)NN * 64;      // NN*128 fp8 = NN*32 ints

    int*    bcnt    = ws_i + o_bcnt;
    int*    bcur    = ws_i + o_bcur;
    float*  gsum    = ws_f + o_gsum;
    int*    bptr    = ws_i + o_bptr;
    int*    row_ptr = ws_i + o_rowp;
    int*    bedges  = ws_i + o_bed;
    int*    col_src = ws_i + o_col;
    short*  whi     = (short*)(ws_i + o_whi);
    short*  wlo     = (short*)(ws_i + o_wlo);
    ushort* x16     = (ushort*)(ws_i + o_x16);
    ushort* aggr    = (ushort*)(ws_i + o_aggr);
    ushort* hA      = (ushort*)(ws_i + o_hA);
    ushort* hB      = (ushort*)(ws_i + o_hB);
    unsigned char* h8 = (unsigned char*)(ws_i + o_h8);

    short* W1l_hi = whi + 0;     short* W1l_lo = wlo + 0;
    short* W1r_hi = whi + 4096;  short* W1r_lo = wlo + 4096;
    short* W2l_hi = whi + 8192;  short* W2l_lo = wlo + 8192;
    short* W2r_hi = whi + 24576; short* W2r_lo = wlo + 24576;
    short* W3l_hi = whi + 40960; short* W3l_lo = wlo + 40960;
    short* W3r_hi = whi + 57344; short* W3r_lo = wlo + 57344;

    // zero bcnt, bcur, gsum
    hipMemsetAsync(d_ws, 0, 640 * sizeof(int), stream);

    const int TB = 256;
    dim3 blk(TB);

    // independent prep
    to_bf16<<<(NN * 32 / 4 + TB - 1) / TB, blk, 0, stream>>>(x, x16, NN * 32);
    split_weights<<<(73728 + TB - 1) / TB, blk, 0, stream>>>(
        W1l, W1r, W2l, W2r, W3l, W3r, whi, wlo);

    // bucketed CSR build (coarse 512-node buckets)
    bucket_hist<<<256, blk, 0, stream>>>(edges, E, bcnt);
    scan_bptr<<<1, 256, 0, stream>>>(bcnt, bptr);
    bucket_scatter<<<(E + SCAT_CHUNK - 1) / SCAT_CHUNK, blk, 0, stream>>>(
        edges, E, bptr, bcur, bedges);
    bucket_csr512<<<NBC, blk, 0, stream>>>(bedges, bptr, row_ptr, col_src);

    dim3 grid_agg((size_t)NN * 64 / TB);   // 25000: one wave per node
    dim3 grid_f8((NN * 16 + TB - 1) / TB); // NN*128/8 groups
    dim3 grid_g(512);                      // 256 blocks per col-half

    // Layer 1 (K=32, relu)
    aggregate32_bf16<<<grid_agg, blk, 0, stream>>>(x16, row_ptr, col_src, aggr, NN);
    gemm32<32, true, false><<<grid_g, blk, 0, stream>>>(
        aggr, x16, W1l_hi, W1l_lo, W1r_hi, W1r_lo, b1, hA, nullptr);

    // Layer 2 (K=128, relu): gather hA in fp8
    to_fp8<<<grid_f8, blk, 0, stream>>>(hA, h8, NN * 16);
    aggregate128_fp8<<<grid_agg, blk, 0, stream>>>(h8, row_ptr, col_src, aggr, NN);
    gemm32<128, true, false><<<grid_g, blk, 0, stream>>>(
        aggr, hA, W2l_hi, W2l_lo, W2r_hi, W2r_lo, b2, hB, nullptr);

    // Layer 3 (K=128, fused column-mean into gsum): gather hB in fp8
    to_fp8<<<grid_f8, blk, 0, stream>>>(hB, h8, NN * 16);
    aggregate128_fp8<<<grid_agg, blk, 0, stream>>>(h8, row_ptr, col_src, aggr, NN);
    gemm32<128, false, true><<<grid_g, blk, 0, stream>>>(
        aggr, hB, W3l_hi, W3l_lo, W3r_hi, W3r_lo, b3, nullptr, gsum);

    // Heads (b3 folded into global mean here)
    heads_kernel<<<1, 256, 0, stream>>>(gsum, b3, Pw1, Pb1, Pw2, Pb2,
                                        Vw1, Vb1, Vw2, Vb2, outp,
                                        1.0f / (float)NN);
}

// Round 16
// 305.925 us; speedup vs baseline: 1.9480x; 1.0334x over previous
//
#include <hip/hip_runtime.h>
#include <hip/hip_bf16.h>

#define NN   100000
#define HIDD 128
#define NBC  196          // ceil(NN/512) coarse buckets of 512 nodes

typedef __attribute__((ext_vector_type(8))) short bf16x8;
typedef __attribute__((ext_vector_type(2))) float f32x2;
typedef __attribute__((ext_vector_type(4))) float f32x4;
typedef __attribute__((ext_vector_type(16))) float f32x16;

// RNE fp32 -> bf16 bits
__device__ __forceinline__ short bf16_rne(float v) {
    unsigned u = __float_as_uint(v);
    unsigned r = (u + 0x7fffu + ((u >> 16) & 1u)) >> 16;
    return (short)r;
}
__device__ __forceinline__ float bf16_to_f32(short b) {
    return __uint_as_float(((unsigned)(unsigned short)b) << 16);
}
__device__ __forceinline__ float bf16u_to_f32(ushort b) {
    return __uint_as_float(((unsigned)b) << 16);
}
__device__ __forceinline__ f32x2 unpack2p(unsigned u) {
    f32x2 r;
    r[0] = __uint_as_float((u & 0xFFFFu) << 16);
    r[1] = __uint_as_float(u & 0xFFFF0000u);
    return r;
}
__device__ __forceinline__ unsigned pack2(float a, float b) {
    return ((unsigned)(unsigned short)bf16_rne(a)) |
           (((unsigned)(unsigned short)bf16_rne(b)) << 16);
}

// ---------------------------------------------------------------------------
// Bucketed CSR build. bucket = dst >> 9 (512 nodes per bucket).
// ---------------------------------------------------------------------------
__global__ __launch_bounds__(256)
void bucket_hist(const int* __restrict__ edges, int n_edges,
                 int* __restrict__ bcnt) {
    __shared__ int lh[NBC];
    for (int i = threadIdx.x; i < NBC; i += 256) lh[i] = 0;
    __syncthreads();
    int stride = gridDim.x * blockDim.x;
    for (int e = blockIdx.x * blockDim.x + threadIdx.x; e < n_edges; e += stride) {
        int d = edges[n_edges + e];
        if ((unsigned)d < NN) atomicAdd(&lh[d >> 9], 1);
    }
    __syncthreads();
    for (int i = threadIdx.x; i < NBC; i += 256)
        if (lh[i]) atomicAdd(&bcnt[i], lh[i]);
}

__global__ void scan_bptr(const int* __restrict__ bcnt, int* __restrict__ bptr) {
    __shared__ int lds[256];
    int t = threadIdx.x;
    lds[t] = (t < NBC) ? bcnt[t] : 0;
    __syncthreads();
    for (int off = 1; off < 256; off <<= 1) {
        int u = (t >= off) ? lds[t - off] : 0;
        __syncthreads();
        lds[t] += u;
        __syncthreads();
    }
    if (t < NBC) bptr[t + 1] = lds[t];
    if (t == 0) bptr[0] = 0;
}

// Scatter edges into bucket regions as packed (dst_local<<17 | src).
#define SCAT_CHUNK 4096
__global__ __launch_bounds__(256)
void bucket_scatter(const int* __restrict__ edges, int n_edges,
                    const int* __restrict__ bptr, int* __restrict__ bcur,
                    int* __restrict__ bedges) {
    __shared__ int lh[NBC];
    __shared__ int lbase[NBC];
    int t = threadIdx.x;
    int base = blockIdx.x * SCAT_CHUNK;
    for (int i = t; i < NBC; i += 256) lh[i] = 0;
    __syncthreads();
#pragma unroll
    for (int i = 0; i < SCAT_CHUNK / 256; ++i) {
        int e = base + i * 256 + t;
        if (e < n_edges) {
            int d = edges[n_edges + e];
            if ((unsigned)d < NN) atomicAdd(&lh[d >> 9], 1);
        }
    }
    __syncthreads();
    for (int i = t; i < NBC; i += 256) {
        int c = lh[i];
        lbase[i] = (c > 0) ? atomicAdd(&bcur[i], c) : 0;
        lh[i] = 0;   // reuse as cursor
    }
    __syncthreads();
#pragma unroll
    for (int i = 0; i < SCAT_CHUNK / 256; ++i) {
        int e = base + i * 256 + t;
        if (e < n_edges) {
            int s = edges[e];
            int d = edges[n_edges + e];
            if ((unsigned)d < NN && (unsigned)s < NN) {
                int b = d >> 9;
                int off = atomicAdd(&lh[b], 1);
                bedges[bptr[b] + lbase[b] + off] = ((d & 511) << 17) | s;
            }
        }
    }
}

// One block per 512-node bucket: count -> pairwise scan -> place.
__global__ __launch_bounds__(256)
void bucket_csr512(const int* __restrict__ bedges, const int* __restrict__ bptr,
                   int* __restrict__ row_ptr, int* __restrict__ col_src) {
    __shared__ int lcnt[512];
    __shared__ int lsum[256];
    __shared__ int lexcl[512];
    int b = blockIdx.x;
    int t = threadIdx.x;
    int beg = bptr[b], end = bptr[b + 1];
    lcnt[t] = 0; lcnt[t + 256] = 0;
    __syncthreads();
    for (int e = beg + t; e < end; e += 256)
        atomicAdd(&lcnt[bedges[e] >> 17], 1);
    __syncthreads();
    int a0 = lcnt[2 * t], a1 = lcnt[2 * t + 1];
    lsum[t] = a0 + a1;
    __syncthreads();
    for (int off = 1; off < 256; off <<= 1) {
        int u = (t >= off) ? lsum[t - off] : 0;
        __syncthreads();
        lsum[t] += u;
        __syncthreads();
    }
    int pairExcl = lsum[t] - (a0 + a1);     // exclusive prefix of element 2t
    lexcl[2 * t]     = pairExcl;
    lexcl[2 * t + 1] = pairExcl + a0;
    int node0 = b << 9;
    int n0 = node0 + 2 * t, n1 = node0 + 2 * t + 1;
    if (n0 < NN) row_ptr[n0] = beg + pairExcl;
    if (n1 < NN) row_ptr[n1] = beg + pairExcl + a0;
    lcnt[2 * t] = 0; lcnt[2 * t + 1] = 0;   // reuse as cursors
    if (b == NBC - 1 && t == 0) row_ptr[NN] = end;
    __syncthreads();
    for (int e = beg + t; e < end; e += 256) {
        int p = bedges[e];
        int dl = p >> 17, src = p & 0x1FFFF;
        int pos = atomicAdd(&lcnt[dl], 1);
        col_src[beg + lexcl[dl] + pos] = src;
    }
}

// ---------------------------------------------------------------------------
// fp32 -> bf16 conversion (x)
// ---------------------------------------------------------------------------
__global__ void to_bf16(const float* __restrict__ in, ushort* __restrict__ out, int n) {
    int i = (blockIdx.x * blockDim.x + threadIdx.x) * 4;
    if (i + 3 >= n) {
        for (int k = i; k < n; ++k) out[k] = (ushort)bf16_rne(in[k]);
        return;
    }
    float4 v = *(const float4*)&in[i];
    unsigned lo = pack2(v.x, v.y), hi = pack2(v.z, v.w);
    *(uint2*)&out[i] = make_uint2(lo, hi);
}

// ---------------------------------------------------------------------------
// fp8 pull-mode mean aggregation: one wave per node, row = 128B.
// Packed f32x2 accumulation (v_pk_add_f32) halves add-instruction count.
// ---------------------------------------------------------------------------
__device__ __forceinline__ void acc_fp8x8p(f32x2* s, uint2 u) {
    s[0] += __builtin_amdgcn_cvt_pk_f32_fp8(u.x, false);
    s[1] += __builtin_amdgcn_cvt_pk_f32_fp8(u.x, true);
    s[2] += __builtin_amdgcn_cvt_pk_f32_fp8(u.y, false);
    s[3] += __builtin_amdgcn_cvt_pk_f32_fp8(u.y, true);
}

__global__ void aggregate128_fp8(const unsigned char* __restrict__ h8,
                                 const int* __restrict__ row_ptr,
                                 const int* __restrict__ col_src,
                                 ushort* __restrict__ aggr16, int n_nodes) {
    int node = (int)((blockIdx.x * (size_t)blockDim.x + threadIdx.x) >> 6);
    int lane = threadIdx.x & 63;
    if (node >= n_nodes) return;
    const int g   = lane >> 4;        // neighbor group 0..3
    const int seg = lane & 15;        // 8B segment within 128B row
    int beg = row_ptr[node], end = row_ptr[node + 1];
    f32x2 s[4];
#pragma unroll
    for (int e = 0; e < 4; ++e) s[e] = (f32x2){0.f, 0.f};
    int j = beg;
    for (; j + 8 <= end; j += 8) {                 // 2 batches in flight
        int i0 = col_src[j + g];
        int i1 = col_src[j + 4 + g];
        uint2 u0 = *(const uint2*)&h8[(size_t)i0 * HIDD + seg * 8];
        uint2 u1 = *(const uint2*)&h8[(size_t)i1 * HIDD + seg * 8];
        acc_fp8x8p(s, u0);
        acc_fp8x8p(s, u1);
    }
    for (; j + 4 <= end; j += 4) {
        int i0 = col_src[j + g];
        uint2 u0 = *(const uint2*)&h8[(size_t)i0 * HIDD + seg * 8];
        acc_fp8x8p(s, u0);
    }
    int rem = end - j;
    if (g < rem) {                                 // masked tail, one step
        int i0 = col_src[j + g];
        uint2 u0 = *(const uint2*)&h8[(size_t)i0 * HIDD + seg * 8];
        acc_fp8x8p(s, u0);
    }
    // reduce across the 4 groups
#pragma unroll
    for (int e = 0; e < 4; ++e) {
        s[e][0] += __shfl_xor(s[e][0], 16);
        s[e][1] += __shfl_xor(s[e][1], 16);
        s[e][0] += __shfl_xor(s[e][0], 32);
        s[e][1] += __shfl_xor(s[e][1], 32);
    }
    float inv = (end > beg) ? 1.0f / (float)(end - beg) : 0.0f;
    if (lane < 16) {
        unsigned r0 = pack2(s[0][0] * inv, s[0][1] * inv);
        unsigned r1 = pack2(s[1][0] * inv, s[1][1] * inv);
        unsigned r2 = pack2(s[2][0] * inv, s[2][1] * inv);
        unsigned r3 = pack2(s[3][0] * inv, s[3][1] * inv);
        *(uint4*)&aggr16[(size_t)node * HIDD + seg * 8] = make_uint4(r0, r1, r2, r3);
    }
}

// One wave per node; 4 lanes x 16B cover one 64B row; 16 groups =>
// 16 neighbors per load instruction. Packed f32x2 accumulation.
__global__ void aggregate32_bf16(const ushort* __restrict__ x16,
                                 const int* __restrict__ row_ptr,
                                 const int* __restrict__ col_src,
                                 ushort* __restrict__ aggr16, int n_nodes) {
    int node = (int)((blockIdx.x * (size_t)blockDim.x + threadIdx.x) >> 6);
    int lane = threadIdx.x & 63;
    if (node >= n_nodes) return;
    const int g   = lane >> 2;        // neighbor group 0..15
    const int seg = lane & 3;         // 16B segment within 64B row
    int beg = row_ptr[node], end = row_ptr[node + 1];
    f32x2 s[4];
#pragma unroll
    for (int e = 0; e < 4; ++e) s[e] = (f32x2){0.f, 0.f};
    int j = beg;
    for (; j + 16 <= end; j += 16) {
        int i0 = col_src[j + g];
        uint4 u = *(const uint4*)&x16[(size_t)i0 * 32 + seg * 8];
        s[0] += unpack2p(u.x);
        s[1] += unpack2p(u.y);
        s[2] += unpack2p(u.z);
        s[3] += unpack2p(u.w);
    }
    int rem = end - j;
    if (g < rem) {                                 // masked tail (up to 15)
        int i0 = col_src[j + g];
        uint4 u = *(const uint4*)&x16[(size_t)i0 * 32 + seg * 8];
        s[0] += unpack2p(u.x);
        s[1] += unpack2p(u.y);
        s[2] += unpack2p(u.z);
        s[3] += unpack2p(u.w);
    }
    // reduce across the 16 groups
#pragma unroll
    for (int e = 0; e < 4; ++e) {
#pragma unroll
        for (int h = 0; h < 2; ++h) {
            s[e][h] += __shfl_xor(s[e][h], 4);
            s[e][h] += __shfl_xor(s[e][h], 8);
            s[e][h] += __shfl_xor(s[e][h], 16);
            s[e][h] += __shfl_xor(s[e][h], 32);
        }
    }
    float inv = (end > beg) ? 1.0f / (float)(end - beg) : 0.0f;
    if (lane < 4) {
        unsigned r0 = pack2(s[0][0] * inv, s[0][1] * inv);
        unsigned r1 = pack2(s[1][0] * inv, s[1][1] * inv);
        unsigned r2 = pack2(s[2][0] * inv, s[2][1] * inv);
        unsigned r3 = pack2(s[3][0] * inv, s[3][1] * inv);
        *(uint4*)&aggr16[(size_t)node * 32 + seg * 8] = make_uint4(r0, r1, r2, r3);
    }
}

// ---------------------------------------------------------------------------
// Weight pre-split: fp32 -> (hi, lo) bf16 planes, all 6 conv matrices.
// ---------------------------------------------------------------------------
__global__ void split_weights(const float* __restrict__ W1l, const float* __restrict__ W1r,
                              const float* __restrict__ W2l, const float* __restrict__ W2r,
                              const float* __restrict__ W3l, const float* __restrict__ W3r,
                              short* __restrict__ whi, short* __restrict__ wlo) {
    int i = blockIdx.x * blockDim.x + threadIdx.x;
    if (i >= 73728) return;
    const float* src; int off;
    if (i < 4096)       { src = W1l; off = 0; }
    else if (i < 8192)  { src = W1r; off = 4096; }
    else if (i < 24576) { src = W2l; off = 8192; }
    else if (i < 40960) { src = W2r; off = 24576; }
    else if (i < 57344) { src = W3l; off = 40960; }
    else                { src = W3r; off = 57344; }
    float v = src[i - off];
    short h = bf16_rne(v);
    float l = v - bf16_to_f32(h);
    whi[i] = h;
    wlo[i] = bf16_rne(l);
}

// ---------------------------------------------------------------------------
// 32x32x16-MFMA dual GEMM, W in LDS, A from global (r13 structure).
// FP8OUT: epilogue also emits fp8 e4m3 copy (feeds next layer's gather),
// removing the separate to_fp8 pass (launch + 38MB round-trip).
// ---------------------------------------------------------------------------
template <int KA, bool RELU, bool MEAN, bool FP8OUT>
__global__ __launch_bounds__(256)
void gemm32(const ushort* __restrict__ inA, const ushort* __restrict__ inB,
            const short* __restrict__ WAhi, const short* __restrict__ WAlo,
            const short* __restrict__ WBhi, const short* __restrict__ WBlo,
            const float* __restrict__ bias,
            ushort* __restrict__ out, unsigned char* __restrict__ out8,
            float* __restrict__ gsum) {
    constexpr int NCH = KA / 16;            // k-chunks of 16
    constexpr int NT  = (NN + 63) / 64;     // 1563 row tiles (last is half)
    __shared__ __align__(16) ushort sW[4096 * NCH];  // 64KB at KA=128

    const int t = threadIdx.x;
    const int wave = t >> 6, lane = t & 63;
    const int half  = blockIdx.x & 1;
    const int strip = wave & 1;             // 32-col strip within the half
    const int rhalf = wave >> 1;            // 32-row half within the 64-row tile
    const int col = lane & 31;
    const int kh  = lane >> 5;              // k-half of the fragment
    const int o0 = half * 64 + strip * 32;

    // ---- stage W (hi+lo, both ops) for this 64-col half; dst is linear ----
    for (int i = t; i < 512 * NCH; i += 256) {
        int st  = i / (256 * NCH);
        int rem = i % (256 * NCH);
        int f   = rem >> 6;                 // (op*NCH+ch)*2+pl
        int w   = rem & 63;
        int wkh = w >> 5, wcol = w & 31;
        int op = f / (NCH * 2);
        int r2 = f % (NCH * 2);
        int ch = r2 >> 1, pl = r2 & 1;
        const short* Wp = op ? (pl ? WBlo : WBhi) : (pl ? WAlo : WAhi);
        bf16x8 v = *(const bf16x8*)&Wp[(size_t)(half * 64 + st * 32 + wcol) * KA
                                       + ch * 16 + wkh * 8];
        *(bf16x8*)&sW[(size_t)i * 8] = v;
    }
    __syncthreads();

    const int sbase = strip * (2048 * NCH) + kh * 256 + col * 8;
    const float bv = MEAN ? 0.f : bias[o0 + col];
    float csum = 0.f;

    for (int rt = blockIdx.x >> 1; rt < NT; rt += (gridDim.x >> 1)) {
        const int r0 = rt * 64 + rhalf * 32;
        const int ar = min(r0 + col, NN - 1);     // clamped load row
        f32x16 acc = {0.f,0.f,0.f,0.f,0.f,0.f,0.f,0.f,
                      0.f,0.f,0.f,0.f,0.f,0.f,0.f,0.f};
#pragma unroll
        for (int op = 0; op < 2; ++op) {
            const ushort* __restrict__ in = op ? inB : inA;
            const ushort* ab = in + (size_t)ar * KA + kh * 8;
            bf16x8 a[NCH];
#pragma unroll
            for (int ch = 0; ch < NCH; ++ch) a[ch] = *(const bf16x8*)(ab + ch * 16);
#pragma unroll
            for (int ch = 0; ch < NCH; ++ch) {
                bf16x8 wh = *(const bf16x8*)&sW[sbase + ((op * NCH + ch) * 2 + 0) * 512];
                acc = __builtin_amdgcn_mfma_f32_32x32x16_bf16(a[ch], wh, acc, 0, 0, 0);
                bf16x8 wl = *(const bf16x8*)&sW[sbase + ((op * NCH + ch) * 2 + 1) * 512];
                acc = __builtin_amdgcn_mfma_f32_32x32x16_bf16(a[ch], wl, acc, 0, 0, 0);
            }
        }
        if (r0 < NN) {                      // whole 32-row group valid or not
            if (!MEAN) {
                const int o = o0 + col;
                const int rb = r0 + 4 * kh;
#pragma unroll
                for (int reg = 0; reg < 16; reg += 2) {
                    int ra = rb + (reg & 3) + 8 * (reg >> 2);   // pair rows ra, ra+1
                    float v0 = acc[reg] + bv;
                    float v1 = acc[reg + 1] + bv;
                    if (RELU) { v0 = fmaxf(v0, 0.f); v1 = fmaxf(v1, 0.f); }
                    out[(size_t)ra * HIDD + o]       = (ushort)bf16_rne(v0);
                    out[(size_t)(ra + 1) * HIDD + o] = (ushort)bf16_rne(v1);
                    if (FP8OUT) {
                        unsigned w = __builtin_amdgcn_cvt_pk_fp8_f32(v0, v1, 0u, false);
                        out8[(size_t)ra * HIDD + o]       = (unsigned char)(w & 0xFF);
                        out8[(size_t)(ra + 1) * HIDD + o] = (unsigned char)((w >> 8) & 0xFF);
                    }
                }
            } else {
#pragma unroll
                for (int reg = 0; reg < 16; ++reg) csum += acc[reg];
            }
        }
    }

    if (MEAN) {
        csum += __shfl_xor(csum, 32);       // combine the two row-subsets
        if (lane < 32) atomicAdd(&gsum[o0 + col], csum);
    }
}

// ---------------------------------------------------------------------------
// Heads: g = gsum/N + b3; logits = relu(g@Pw1.T+Pb1)@Pw2.T+Pb2; value likewise.
// ---------------------------------------------------------------------------
__global__ void heads_kernel(const float* __restrict__ gsum,
                             const float* __restrict__ b3,
                             const float* __restrict__ Pw1, const float* __restrict__ Pb1,
                             const float* __restrict__ Pw2, const float* __restrict__ Pb2,
                             const float* __restrict__ Vw1, const float* __restrict__ Vb1,
                             const float* __restrict__ Vw2, const float* __restrict__ Vb2,
                             float* __restrict__ out, float inv_n) {
    __shared__ float g[128], a1[128], v1[128];
    int t = threadIdx.x;
    if (t < 128) g[t] = gsum[t] * inv_n + b3[t];
    __syncthreads();
    if (t < 128) {
        float s = Pb1[t];
        for (int f = 0; f < 128; ++f) s = fmaf(Pw1[t * 128 + f], g[f], s);
        a1[t] = fmaxf(s, 0.f);
    } else {
        int o = t - 128;
        float s = Vb1[o];
        for (int f = 0; f < 128; ++f) s = fmaf(Vw1[o * 128 + f], g[f], s);
        v1[o] = fmaxf(s, 0.f);
    }
    __syncthreads();
    if (t < 6) {
        float s = Pb2[t];
        for (int f = 0; f < 128; ++f) s = fmaf(Pw2[t * 128 + f], a1[f], s);
        out[t] = s;
    }
    if (t == 6) {
        float s = Vb2[0];
        for (int f = 0; f < 128; ++f) s = fmaf(Vw2[f], v1[f], s);
        out[6] = s;
    }
}

// ---------------------------------------------------------------------------
extern "C" void kernel_launch(void* const* d_in, const int* in_sizes, int n_in,
                              void* d_out, int out_size, void* d_ws, size_t ws_size,
                              hipStream_t stream) {
    const float* x    = (const float*)d_in[0];
    const int*   edges = (const int*)d_in[1];
    const float* W1l = (const float*)d_in[2];
    const float* b1  = (const float*)d_in[3];
    const float* W1r = (const float*)d_in[4];
    const float* W2l = (const float*)d_in[5];
    const float* b2  = (const float*)d_in[6];
    const float* W2r = (const float*)d_in[7];
    const float* W3l = (const float*)d_in[8];
    const float* b3  = (const float*)d_in[9];
    const float* W3r = (const float*)d_in[10];
    const float* Pw1 = (const float*)d_in[11];
    const float* Pb1 = (const float*)d_in[12];
    const float* Pw2 = (const float*)d_in[13];
    const float* Pb2 = (const float*)d_in[14];
    const float* Vw1 = (const float*)d_in[15];
    const float* Vb1 = (const float*)d_in[16];
    const float* Vw2 = (const float*)d_in[17];
    const float* Vb2 = (const float*)d_in[18];
    float* outp = (float*)d_out;

    const int E = in_sizes[1] / 2;

    // ---- workspace layout (int offsets, regions 256B-aligned) ----
    int*   ws_i = (int*)d_ws;
    float* ws_f = (float*)d_ws;
    size_t o_bcnt = 0;                 // NBC ints  (zeroed)
    size_t o_bcur = 256;               // NBC ints  (zeroed)
    size_t o_gsum = 512;               // 128 f32   (zeroed)
    size_t o_bptr = 640;               // NBC+1
    size_t o_rowp = 896;               // NN+1
    size_t o_bed  = 100928;            // E packed bucket edges
    size_t o_col  = o_bed + (size_t)E;           // E
    size_t o_whi  = ((o_col + (size_t)E + 63) / 64) * 64;  // 73728 shorts = 36864 ints
    size_t o_wlo  = o_whi + 36864;
    size_t o_x16  = o_wlo + 36864;               // NN*32 bf16 = NN*16 ints
    size_t o_aggr = o_x16 + (size_t)NN * 16;     // NN*128 bf16 = NN*64 ints
    size_t o_hA   = o_aggr + (size_t)NN * 64;
    size_t o_hB   = o_hA + (size_t)NN * 64;
    size_t o_h8   = o_hB + (size_t)NN * 64;      // NN*128 fp8 = NN*32 ints

    int*    bcnt    = ws_i + o_bcnt;
    int*    bcur    = ws_i + o_bcur;
    float*  gsum    = ws_f + o_gsum;
    int*    bptr    = ws_i + o_bptr;
    int*    row_ptr = ws_i + o_rowp;
    int*    bedges  = ws_i + o_bed;
    int*    col_src = ws_i + o_col;
    short*  whi     = (short*)(ws_i + o_whi);
    short*  wlo     = (short*)(ws_i + o_wlo);
    ushort* x16     = (ushort*)(ws_i + o_x16);
    ushort* aggr    = (ushort*)(ws_i + o_aggr);
    ushort* hA      = (ushort*)(ws_i + o_hA);
    ushort* hB      = (ushort*)(ws_i + o_hB);
    unsigned char* h8 = (unsigned char*)(ws_i + o_h8);

    short* W1l_hi = whi + 0;     short* W1l_lo = wlo + 0;
    short* W1r_hi = whi + 4096;  short* W1r_lo = wlo + 4096;
    short* W2l_hi = whi + 8192;  short* W2l_lo = wlo + 8192;
    short* W2r_hi = whi + 24576; short* W2r_lo = wlo + 24576;
    short* W3l_hi = whi + 40960; short* W3l_lo = wlo + 40960;
    short* W3r_hi = whi + 57344; short* W3r_lo = wlo + 57344;

    // zero bcnt, bcur, gsum
    hipMemsetAsync(d_ws, 0, 640 * sizeof(int), stream);

    const int TB = 256;
    dim3 blk(TB);

    // independent prep
    to_bf16<<<(NN * 32 / 4 + TB - 1) / TB, blk, 0, stream>>>(x, x16, NN * 32);
    split_weights<<<(73728 + TB - 1) / TB, blk, 0, stream>>>(
        W1l, W1r, W2l, W2r, W3l, W3r, whi, wlo);

    // bucketed CSR build (coarse 512-node buckets)
    bucket_hist<<<256, blk, 0, stream>>>(edges, E, bcnt);
    scan_bptr<<<1, 256, 0, stream>>>(bcnt, bptr);
    bucket_scatter<<<(E + SCAT_CHUNK - 1) / SCAT_CHUNK, blk, 0, stream>>>(
        edges, E, bptr, bcur, bedges);
    bucket_csr512<<<NBC, blk, 0, stream>>>(bedges, bptr, row_ptr, col_src);

    dim3 grid_agg((size_t)NN * 64 / TB);   // 25000: one wave per node
    dim3 grid_g(512);                      // 256 blocks per col-half

    // Layer 1 (K=32, relu): epilogue also writes fp8 hA for layer-2 gather
    aggregate32_bf16<<<grid_agg, blk, 0, stream>>>(x16, row_ptr, col_src, aggr, NN);
    gemm32<32, true, false, true><<<grid_g, blk, 0, stream>>>(
        aggr, x16, W1l_hi, W1l_lo, W1r_hi, W1r_lo, b1, hA, h8, nullptr);

    // Layer 2 (K=128, relu): epilogue writes fp8 hB for layer-3 gather
    aggregate128_fp8<<<grid_agg, blk, 0, stream>>>(h8, row_ptr, col_src, aggr, NN);
    gemm32<128, true, false, true><<<grid_g, blk, 0, stream>>>(
        aggr, hA, W2l_hi, W2l_lo, W2r_hi, W2r_lo, b2, hB, h8, nullptr);

    // Layer 3 (K=128, fused column-mean into gsum)
    aggregate128_fp8<<<grid_agg, blk, 0, stream>>>(h8, row_ptr, col_src, aggr, NN);
    gemm32<128, false, true, false><<<grid_g, blk, 0, stream>>>(
        aggr, hB, W3l_hi, W3l_lo, W3r_hi, W3r_lo, b3, nullptr, nullptr, gsum);

    // Heads (b3 folded into global mean here)
    heads_kernel<<<1, 256, 0, stream>>>(gsum, b3, Pw1, Pb1, Pw2, Pb2,
                                        Vw1, Vb1, Vw2, Vb2, outp,
                                        1.0f / (float)NN);
}